// Round 2
// baseline (1154.427 us; speedup 1.0000x reference)
//
#include <hip/hip_runtime.h>
#include <hip/hip_bf16.h>

// ---------- helpers ----------
static __device__ __forceinline__ float bf2f(unsigned short u) {
  return __uint_as_float(((unsigned)u) << 16);
}
static __device__ __forceinline__ unsigned short f2bf(float f) {
  unsigned u = __float_as_uint(f);
  u += 0x7fffu + ((u >> 16) & 1u);   // RNE
  return (unsigned short)(u >> 16);
}
static __device__ __forceinline__ unsigned packbf(float a, float b) {
  return (unsigned)f2bf(a) | ((unsigned)f2bf(b) << 16);
}
// order-preserving float<->uint for atomicMax (0 == -inf identity)
static __device__ __forceinline__ unsigned encf(float f) {
  unsigned u = __float_as_uint(f);
  return (u & 0x80000000u) ? ~u : (u | 0x80000000u);
}
static __device__ __forceinline__ float decf(unsigned u) {
  return (u & 0x80000000u) ? __uint_as_float(u ^ 0x80000000u)
                           : __uint_as_float(~u);
}
static __device__ __forceinline__ float pd(unsigned a, unsigned b) {
  return bf2f((unsigned short)a) * bf2f((unsigned short)b)
       + bf2f((unsigned short)(a >> 16)) * bf2f((unsigned short)(b >> 16));
}
static __device__ __forceinline__ float gelu_tanh(float a) {
  float t = tanhf(0.7978845608028654f * (a + 0.044715f * a * a * a));
  return 0.5f * a * (1.0f + t);
}

// param-block element offsets (bf16 canonical)
#define PC_G1   0
#define PC_B1   128
#define PC_WQ   256
#define PC_BQ   16640
#define PC_WK   16768
#define PC_BK   33152
#define PC_WV   33280
#define PC_BV   49664
#define PC_EB   49792
#define PC_WO   49824
#define PC_BO   66208
#define PC_G2   66336
#define PC_B2   66464
#define PC_W1   66592
#define PC_B1F  99360
#define PC_W2   99616
#define PC_B2F  132384
#define PC_TOT  132512

// ---------- dtype detect: votes on low-16-bits-as-bf16 plausibility ----------
__global__ void k_detect(const unsigned* __restrict__ x, int* __restrict__ flag) {
  __shared__ int cnt;
  if (threadIdx.x == 0) cnt = 0;
  __syncthreads();
  int good = 0;
  for (int i = threadIdx.x; i < 1024; i += 256) {
    float v = fabsf(bf2f((unsigned short)(x[i] & 0xFFFFu)));
    good += (v >= 0.0009765625f && v <= 32.0f) ? 1 : 0;
  }
  atomicAdd(&cnt, good);
  __syncthreads();
  if (threadIdx.x == 0) flag[0] = (cnt < 512) ? 1 : 0;   // 1 => inputs are f32
}

// ---------- canonicalize all float params to bf16 block ----------
struct PP { const void* p[17]; };
__global__ __launch_bounds__(256) void k_convert(
    PP pp, const int* __restrict__ flag, unsigned short* __restrict__ pc)
{
  const int offs[18] = {PC_G1,PC_B1,PC_WQ,PC_BQ,PC_WK,PC_BK,PC_WV,PC_BV,PC_EB,
                        PC_WO,PC_BO,PC_G2,PC_B2,PC_W1,PC_B1F,PC_W2,PC_B2F,PC_TOT};
  int i = blockIdx.x * 256 + threadIdx.x;
  if (i >= PC_TOT) return;
  int s = 0;
  while (i >= offs[s + 1]) ++s;
  int local = i - offs[s];
  if (flag[0])
    pc[i] = f2bf(((const float*)pp.p[s])[local]);
  else
    pc[i] = ((const unsigned short*)pp.p[s])[local];
}

// ---------- generic: LN(xin) @ W-slice + bias (+gelu) -> bf16 dst ----------
// grid = RB * ns blocks; slice s = blockIdx.x % ns; 4 rows per iteration.
__global__ __launch_bounds__(256) void k_ln_mv(
    const void* __restrict__ xin, int xmode /*1: force f32*/,
    const int* __restrict__ flag, const unsigned short* __restrict__ pc,
    int lng_off, int lnb_off, int w_off, int w_rowstride, int w_slice,
    int b_off, int b_slice, unsigned short* __restrict__ dst, int dstride,
    int do_gelu, int ns, int rpb, int N)
{
  __shared__ unsigned short Ws[128 * 128];   // 32 KB
  __shared__ float hs[128 * 4];
  __shared__ float gs[128], bs[128];
  const int tid = threadIdx.x;
  const int s = blockIdx.x % ns;
  const int wbase = w_off + s * w_slice;

  for (int idx = tid; idx < 2048; idx += 256) {
    int i = idx >> 4, j8 = (idx & 15) << 3;
    *(uint4*)&Ws[i * 128 + j8] = *(const uint4*)&pc[wbase + i * w_rowstride + j8];
  }
  if (tid < 128) { gs[tid] = bf2f(pc[lng_off + tid]); bs[tid] = bf2f(pc[lnb_off + tid]); }
  const int cp = tid & 63, rg = tid >> 6;
  const float bias0 = bf2f(pc[b_off + s * b_slice + 2 * cp]);
  const float bias1 = bf2f(pc[b_off + s * b_slice + 2 * cp + 1]);
  const int isf = xmode ? 1 : flag[0];
  __syncthreads();

  int row0 = (blockIdx.x / ns) * rpb;
  int row1 = min(row0 + rpb, N);
  for (int row = row0; row < row1; row += 4) {
    {   // LN: wave rg handles row+rg; lane cp handles elems 2cp, 2cp+1
      int r = row + rg;
      float x0 = 0.f, x1 = 0.f;
      if (r < row1) {
        if (isf) {
          float2 xx = ((const float2*)xin)[(r * 128 + 2 * cp) >> 1];
          x0 = xx.x; x1 = xx.y;
        } else {
          unsigned xx = ((const unsigned*)xin)[(r * 128 + 2 * cp) >> 1];
          x0 = bf2f((unsigned short)xx); x1 = bf2f((unsigned short)(xx >> 16));
        }
      }
      float sm = x0 + x1, s2 = x0 * x0 + x1 * x1;
      #pragma unroll
      for (int o = 32; o; o >>= 1) { sm += __shfl_xor(sm, o); s2 += __shfl_xor(s2, o); }
      float mean = sm * (1.f / 128.f);
      float var = fmaxf(s2 * (1.f / 128.f) - mean * mean, 0.f);
      float inv = rsqrtf(var + 1e-5f);
      hs[(2 * cp) * 4 + rg]     = (x0 - mean) * inv * gs[2 * cp]     + bs[2 * cp];
      hs[(2 * cp + 1) * 4 + rg] = (x1 - mean) * inv * gs[2 * cp + 1] + bs[2 * cp + 1];
    }
    __syncthreads();
    {   // matvec: thread -> (row = row+rg, cols 2cp, 2cp+1)
      float a0 = bias0, a1 = bias1;
      #pragma unroll 8
      for (int i = 0; i < 128; ++i) {
        float h = hs[i * 4 + rg];
        unsigned w = *(const unsigned*)&Ws[i * 128 + 2 * cp];
        a0 += h * bf2f((unsigned short)w);
        a1 += h * bf2f((unsigned short)(w >> 16));
      }
      if (do_gelu) { a0 = gelu_tanh(a0); a1 = gelu_tanh(a1); }
      int r = row + rg;
      if (r < row1)
        *(unsigned*)&dst[r * dstride + s * 128 + 2 * cp] = packbf(a0, a1);
    }
    __syncthreads();
  }
}

// ---------- per-(edge,head) scores + segment max ----------
__global__ __launch_bounds__(256) void k_edge_scores(
    const unsigned short* __restrict__ qkv,
    const int* __restrict__ ei, const int* __restrict__ et,
    const unsigned short* __restrict__ pc,
    float* __restrict__ sbuf, unsigned* __restrict__ menc, int E)
{
  int tt = blockIdx.x * 256 + threadIdx.x;
  if (tt >= E * 8) return;
  int e = tt >> 3, h = tt & 7;
  int s = ei[e], d = ei[E + e];
  const uint4* qp = (const uint4*)(qkv + d * 384 + h * 16);
  const uint4* kp = (const uint4*)(qkv + s * 384 + 128 + h * 16);
  uint4 qa = qp[0], qb = qp[1], ka = kp[0], kb = kp[1];
  float acc = pd(qa.x, ka.x) + pd(qa.y, ka.y) + pd(qa.z, ka.z) + pd(qa.w, ka.w)
            + pd(qb.x, kb.x) + pd(qb.y, kb.y) + pd(qb.z, kb.z) + pd(qb.w, kb.w);
  float sc = acc * 0.25f + bf2f(pc[PC_EB + et[e] * 8 + h]);
  sbuf[tt] = sc;
  atomicMax(&menc[d * 8 + h], encf(sc));
}

// ---------- p = exp(s - m), denom accumulate ----------
__global__ __launch_bounds__(256) void k_edge_softexp(
    const int* __restrict__ ei, const unsigned* __restrict__ menc,
    float* __restrict__ sbuf, float* __restrict__ denom, int E)
{
  int tt = blockIdx.x * 256 + threadIdx.x;
  if (tt >= E * 8) return;
  int e = tt >> 3, h = tt & 7;
  int d = ei[E + e];
  float p = __expf(sbuf[tt] - decf(menc[d * 8 + h]));
  sbuf[tt] = p;
  unsafeAtomicAdd(&denom[d * 8 + h], p);
}

// ---------- msg[dst] += p * v[src] (unnormalized) ----------
__global__ __launch_bounds__(256) void k_edge_msg(
    const int* __restrict__ ei, const float* __restrict__ pbuf,
    const unsigned short* __restrict__ qkv, float* __restrict__ msg, int E)
{
  int t = blockIdx.x * 256 + threadIdx.x;
  if (t >= E * 128) return;
  int e = t >> 7, j = t & 127;
  int s = ei[e], d = ei[E + e];
  float p = pbuf[e * 8 + (j >> 4)];
  float vv = bf2f(qkv[s * 384 + 256 + j]);
  unsafeAtomicAdd(&msg[d * 128 + j], p * vv);
}

// ---------- normalize msg, @wo + bo, residual -> x1 (f32) ----------
__global__ __launch_bounds__(256) void k_attn_out(
    const void* __restrict__ xin, const int* __restrict__ flag,
    const float* __restrict__ msg, const float* __restrict__ denom,
    const unsigned short* __restrict__ pc, float* __restrict__ x1,
    int rpb, int N)
{
  __shared__ unsigned short wos[128 * 128];  // 32 KB
  __shared__ float ms[128 * 4];
  const int tid = threadIdx.x;
  for (int idx = tid; idx < 2048; idx += 256) {
    int i = idx >> 4, j8 = (idx & 15) << 3;
    *(uint4*)&wos[i * 128 + j8] = *(const uint4*)&pc[PC_WO + i * 128 + j8];
  }
  const int cp = tid & 63, rg = tid >> 6;
  const float b0 = bf2f(pc[PC_BO + 2 * cp]), b1 = bf2f(pc[PC_BO + 2 * cp + 1]);
  const int isf = flag[0];
  __syncthreads();

  int row0 = blockIdx.x * rpb;
  int row1 = min(row0 + rpb, N);
  for (int row = row0; row < row1; row += 4) {
    {
      int e = tid & 127, half = tid >> 7;
      #pragma unroll
      for (int kk = 0; kk < 2; ++kk) {
        int r = row + 2 * half + kk;
        ms[e * 4 + 2 * half + kk] =
            (r < row1) ? msg[r * 128 + e] / (denom[r * 8 + (e >> 4)] + 1e-9f) : 0.f;
      }
    }
    __syncthreads();
    {
      float a0 = b0, a1 = b1;
      #pragma unroll 8
      for (int i = 0; i < 128; ++i) {
        float m = ms[i * 4 + rg];
        unsigned w = *(const unsigned*)&wos[i * 128 + 2 * cp];
        a0 += m * bf2f((unsigned short)w);
        a1 += m * bf2f((unsigned short)(w >> 16));
      }
      int r = row + rg;
      if (r < row1) {
        float xr0, xr1;
        if (isf) {
          float2 xx = ((const float2*)xin)[(r * 128 + 2 * cp) >> 1];
          xr0 = xx.x; xr1 = xx.y;
        } else {
          unsigned xx = ((const unsigned*)xin)[(r * 128 + 2 * cp) >> 1];
          xr0 = bf2f((unsigned short)xx); xr1 = bf2f((unsigned short)(xx >> 16));
        }
        float2 o; o.x = xr0 + a0; o.y = xr1 + a1;
        ((float2*)x1)[(r * 128 + 2 * cp) >> 1] = o;
      }
    }
    __syncthreads();
  }
}

// ---------- FFN2: out = x1 + t @ w2 + b2 (dual-dtype out) ----------
__global__ __launch_bounds__(256) void k_ffn2(
    const float* __restrict__ x1, const unsigned short* __restrict__ t,
    const unsigned short* __restrict__ pc, const int* __restrict__ flag,
    void* __restrict__ out, int rpb, int N)
{
  __shared__ unsigned short w2s[256 * 128];  // 64 KB
  const int tid = threadIdx.x;
  for (int idx = tid; idx < 4096; idx += 256)
    *(uint4*)&w2s[idx * 8] = *(const uint4*)&pc[PC_W2 + idx * 8];
  const int cp = tid & 63, rg = tid >> 6;
  const float b0 = bf2f(pc[PC_B2F + 2 * cp]), b1 = bf2f(pc[PC_B2F + 2 * cp + 1]);
  const int isf = flag[0];
  __syncthreads();

  int row0 = blockIdx.x * rpb;
  int row1 = min(row0 + rpb, N);
  for (int row = row0; row < row1; row += 4) {
    int r = row + rg;
    int rr = min(r, N - 1);
    float a0 = b0, a1 = b1;
    #pragma unroll 4
    for (int i8 = 0; i8 < 256; i8 += 8) {
      uint4 tw = *(const uint4*)&t[rr * 256 + i8];
      unsigned tws[4] = {tw.x, tw.y, tw.z, tw.w};
      #pragma unroll
      for (int u = 0; u < 4; ++u) {
        int i = i8 + 2 * u;
        float t0 = bf2f((unsigned short)tws[u]);
        float t1 = bf2f((unsigned short)(tws[u] >> 16));
        unsigned w0 = *(const unsigned*)&w2s[i * 128 + 2 * cp];
        unsigned w1 = *(const unsigned*)&w2s[(i + 1) * 128 + 2 * cp];
        a0 += t0 * bf2f((unsigned short)w0) + t1 * bf2f((unsigned short)w1);
        a1 += t0 * bf2f((unsigned short)(w0 >> 16)) + t1 * bf2f((unsigned short)(w1 >> 16));
      }
    }
    if (r < row1) {
      float2 xv = ((const float2*)x1)[(r * 128 + 2 * cp) >> 1];
      float o0 = xv.x + a0, o1 = xv.y + a1;
      if (isf) {
        float2 o; o.x = o0; o.y = o1;
        ((float2*)out)[(r * 128 + 2 * cp) >> 1] = o;
      } else {
        *(unsigned*)&((unsigned short*)out)[r * 128 + 2 * cp] = packbf(o0, o1);
      }
    }
  }
}

// ---------- launch ----------
extern "C" void kernel_launch(void* const* d_in, const int* in_sizes, int n_in,
                              void* d_out, int out_size, void* d_ws, size_t ws_size,
                              hipStream_t stream)
{
  const void* x = d_in[0];
  const int* ei = (const int*)d_in[1];
  const int* et = (const int*)d_in[2];
  const int N = in_sizes[0] / 128;
  const int E = in_sizes[2];

  char* ws = (char*)d_ws;
  size_t off = 0;
  auto alloc = [&](size_t bytes) -> void* {
    void* p = ws + off; off += (bytes + 255) & ~(size_t)255; return p;
  };
  int* flag = (int*)alloc(4);
  unsigned short* pc = (unsigned short*)alloc((size_t)PC_TOT * 2);
  unsigned short* qkv = (unsigned short*)alloc((size_t)N * 384 * 2);  // x1 overlays
  size_t sb = (size_t)E * 8 * 4;
  size_t tb = (size_t)N * 256 * 2;
  float* sbuf = (float*)alloc(sb > tb ? sb : tb);                      // t overlays
  size_t zoff = off;
  unsigned* menc = (unsigned*)alloc((size_t)N * 8 * 4);
  float* denom   = (float*)alloc((size_t)N * 8 * 4);
  float* msg     = (float*)alloc((size_t)N * 128 * 4);
  hipMemsetAsync(ws + zoff, 0, off - zoff, stream);

  float* x1 = (float*)qkv;
  unsigned short* t = (unsigned short*)sbuf;

  k_detect<<<1, 256, 0, stream>>>((const unsigned*)x, flag);

  PP pp;
  for (int i = 0; i < 17; ++i) pp.p[i] = d_in[5 + i];
  k_convert<<<(PC_TOT + 255) / 256, 256, 0, stream>>>(pp, flag, pc);

  // QKV: 3 slices, RB=391 row-blocks
  {
    int RB = 391, rpb = ((N + RB - 1) / RB + 3) & ~3;
    k_ln_mv<<<RB * 3, 256, 0, stream>>>(x, 0, flag, pc,
        PC_G1, PC_B1, PC_WQ, 128, 16512, PC_BQ, 16512,
        qkv, 384, 0, 3, rpb, N);
  }

  int e8 = E * 8;
  k_edge_scores<<<(e8 + 255) / 256, 256, 0, stream>>>(qkv, ei, et, pc, sbuf, menc, E);
  k_edge_softexp<<<(e8 + 255) / 256, 256, 0, stream>>>(ei, menc, sbuf, denom, E);
  k_edge_msg<<<(E * 128 + 255) / 256, 256, 0, stream>>>(ei, sbuf, qkv, msg, E);

  {
    int RB = 500, rpb = ((N + RB - 1) / RB + 3) & ~3;
    k_attn_out<<<RB, 256, 0, stream>>>(x, flag, msg, denom, pc, x1, rpb, N);
    // FFN1: 2 slices of w1
    k_ln_mv<<<RB * 2, 256, 0, stream>>>(x1, 1, flag, pc,
        PC_G2, PC_B2, PC_W1, 256, 128, PC_B1F, 128,
        t, 256, 1, 2, rpb, N);
    k_ffn2<<<RB, 256, 0, stream>>>(x1, t, pc, flag, d_out, rpb, N);
  }
}

// Round 3
// 916.741 us; speedup vs baseline: 1.2593x; 1.2593x over previous
//
#include <hip/hip_runtime.h>
#include <hip/hip_bf16.h>

// ---------- helpers ----------
static __device__ __forceinline__ float bf2f(unsigned short u) {
  return __uint_as_float(((unsigned)u) << 16);
}
static __device__ __forceinline__ unsigned short f2bf(float f) {
  unsigned u = __float_as_uint(f);
  u += 0x7fffu + ((u >> 16) & 1u);   // RNE
  return (unsigned short)(u >> 16);
}
static __device__ __forceinline__ unsigned packbf(float a, float b) {
  return (unsigned)f2bf(a) | ((unsigned)f2bf(b) << 16);
}
static __device__ __forceinline__ float gelu_tanh(float a) {
  float t = tanhf(0.7978845608028654f * (a + 0.044715f * a * a * a));
  return 0.5f * a * (1.0f + t);
}

// param-block element offsets (bf16 canonical)
#define PC_G1   0
#define PC_B1   128
#define PC_WQ   256
#define PC_BQ   16640
#define PC_WK   16768
#define PC_BK   33152
#define PC_WV   33280
#define PC_BV   49664
#define PC_EB   49792
#define PC_WO   49824
#define PC_BO   66208
#define PC_G2   66336
#define PC_B2   66464
#define PC_W1   66592
#define PC_B1F  99360
#define PC_W2   99616
#define PC_B2F  132384
#define PC_TOT  132512

// ---------- dtype detect: votes on low-16-bits-as-bf16 plausibility ----------
__global__ void k_detect(const unsigned* __restrict__ x, int* __restrict__ flag) {
  __shared__ int cnt;
  if (threadIdx.x == 0) cnt = 0;
  __syncthreads();
  int good = 0;
  for (int i = threadIdx.x; i < 1024; i += 256) {
    float v = fabsf(bf2f((unsigned short)(x[i] & 0xFFFFu)));
    good += (v >= 0.0009765625f && v <= 32.0f) ? 1 : 0;
  }
  atomicAdd(&cnt, good);
  __syncthreads();
  if (threadIdx.x == 0) flag[0] = (cnt < 512) ? 1 : 0;   // 1 => inputs are f32
}

// ---------- canonicalize all float params to bf16 block ----------
struct PP { const void* p[17]; };
__global__ __launch_bounds__(256) void k_convert(
    PP pp, const int* __restrict__ flag, unsigned short* __restrict__ pc)
{
  const int offs[18] = {PC_G1,PC_B1,PC_WQ,PC_BQ,PC_WK,PC_BK,PC_WV,PC_BV,PC_EB,
                        PC_WO,PC_BO,PC_G2,PC_B2,PC_W1,PC_B1F,PC_W2,PC_B2F,PC_TOT};
  int i = blockIdx.x * 256 + threadIdx.x;
  if (i >= PC_TOT) return;
  int s = 0;
  while (i >= offs[s + 1]) ++s;
  int local = i - offs[s];
  if (flag[0])
    pc[i] = f2bf(((const float*)pp.p[s])[local]);
  else
    pc[i] = ((const unsigned short*)pp.p[s])[local];
}

// ---------- generic: LN(xin) @ W-slice + bias (+gelu) -> bf16 dst ----------
__global__ __launch_bounds__(256) void k_ln_mv(
    const void* __restrict__ xin, int xmode /*1: force f32*/,
    const int* __restrict__ flag, const unsigned short* __restrict__ pc,
    int lng_off, int lnb_off, int w_off, int w_rowstride, int w_slice,
    int b_off, int b_slice, unsigned short* __restrict__ dst, int dstride,
    int do_gelu, int ns, int rpb, int N)
{
  __shared__ unsigned short Ws[128 * 128];   // 32 KB
  __shared__ float hs[128 * 4];
  __shared__ float gs[128], bs[128];
  const int tid = threadIdx.x;
  const int s = blockIdx.x % ns;
  const int wbase = w_off + s * w_slice;

  for (int idx = tid; idx < 2048; idx += 256) {
    int i = idx >> 4, j8 = (idx & 15) << 3;
    *(uint4*)&Ws[i * 128 + j8] = *(const uint4*)&pc[wbase + i * w_rowstride + j8];
  }
  if (tid < 128) { gs[tid] = bf2f(pc[lng_off + tid]); bs[tid] = bf2f(pc[lnb_off + tid]); }
  const int cp = tid & 63, rg = tid >> 6;
  const float bias0 = bf2f(pc[b_off + s * b_slice + 2 * cp]);
  const float bias1 = bf2f(pc[b_off + s * b_slice + 2 * cp + 1]);
  const int isf = xmode ? 1 : flag[0];
  __syncthreads();

  int row0 = (blockIdx.x / ns) * rpb;
  int row1 = min(row0 + rpb, N);
  for (int row = row0; row < row1; row += 4) {
    {   // LN: wave rg handles row+rg; lane cp handles elems 2cp, 2cp+1
      int r = row + rg;
      float x0 = 0.f, x1 = 0.f;
      if (r < row1) {
        if (isf) {
          float2 xx = ((const float2*)xin)[(r * 128 + 2 * cp) >> 1];
          x0 = xx.x; x1 = xx.y;
        } else {
          unsigned xx = ((const unsigned*)xin)[(r * 128 + 2 * cp) >> 1];
          x0 = bf2f((unsigned short)xx); x1 = bf2f((unsigned short)(xx >> 16));
        }
      }
      float sm = x0 + x1, s2 = x0 * x0 + x1 * x1;
      #pragma unroll
      for (int o = 32; o; o >>= 1) { sm += __shfl_xor(sm, o); s2 += __shfl_xor(s2, o); }
      float mean = sm * (1.f / 128.f);
      float var = fmaxf(s2 * (1.f / 128.f) - mean * mean, 0.f);
      float inv = rsqrtf(var + 1e-5f);
      hs[(2 * cp) * 4 + rg]     = (x0 - mean) * inv * gs[2 * cp]     + bs[2 * cp];
      hs[(2 * cp + 1) * 4 + rg] = (x1 - mean) * inv * gs[2 * cp + 1] + bs[2 * cp + 1];
    }
    __syncthreads();
    {   // matvec: thread -> (row = row+rg, cols 2cp, 2cp+1)
      float a0 = bias0, a1 = bias1;
      #pragma unroll 8
      for (int i = 0; i < 128; ++i) {
        float h = hs[i * 4 + rg];
        unsigned w = *(const unsigned*)&Ws[i * 128 + 2 * cp];
        a0 += h * bf2f((unsigned short)w);
        a1 += h * bf2f((unsigned short)(w >> 16));
      }
      if (do_gelu) { a0 = gelu_tanh(a0); a1 = gelu_tanh(a1); }
      int r = row + rg;
      if (r < row1)
        *(unsigned*)&dst[r * dstride + s * 128 + 2 * cp] = packbf(a0, a1);
    }
    __syncthreads();
  }
}

// ---------- CSR build ----------
__global__ __launch_bounds__(256) void k_count(
    const int* __restrict__ ei, int* __restrict__ deg, int E)
{
  int e = blockIdx.x * 256 + threadIdx.x;
  if (e < E) atomicAdd(&deg[ei[E + e]], 1);
}

__global__ __launch_bounds__(1024) void k_scan(
    const int* __restrict__ deg, int* __restrict__ rowptr, int N)
{
  __shared__ int wsum[16];
  __shared__ int carry_s;
  const int tid = threadIdx.x, lane = tid & 63, wv = tid >> 6;
  if (tid == 0) carry_s = 0;
  __syncthreads();
  for (int base = 0; base < N; base += 1024) {
    int i = base + tid;
    int v = (i < N) ? deg[i] : 0;
    int s = v;
    #pragma unroll
    for (int o = 1; o < 64; o <<= 1) { int t = __shfl_up(s, o); if (lane >= o) s += t; }
    if (lane == 63) wsum[wv] = s;
    int carry = carry_s;
    __syncthreads();
    if (tid < 16) {
      int ws = wsum[tid];
      #pragma unroll
      for (int o = 1; o < 16; o <<= 1) { int t = __shfl_up(ws, o); if (tid >= o) ws += t; }
      wsum[tid] = ws;
    }
    __syncthreads();
    int woff = wv ? wsum[wv - 1] : 0;
    if (i < N) rowptr[i] = carry + woff + s - v;
    if (tid == 0) carry_s = carry + wsum[15];
    __syncthreads();
  }
  if (threadIdx.x == 0) rowptr[N] = carry_s;
}

__global__ __launch_bounds__(256) void k_scatter(
    const int* __restrict__ ei, const int* __restrict__ et,
    const int* __restrict__ rowptr, int* __restrict__ fill,
    unsigned* __restrict__ packed, int E)
{
  int e = blockIdx.x * 256 + threadIdx.x;
  if (e >= E) return;
  int d = ei[E + e];
  int pos = rowptr[d] + atomicAdd(&fill[d], 1);
  packed[pos] = (unsigned)ei[e] | ((unsigned)et[e] << 18);
}

// ---------- fused per-node attention: scores+softmax+V-agg, no atomics ----------
// block = 128 threads = one dst node; thread j: head h=j>>4, dim d=j&15.
__global__ __launch_bounds__(128) void k_node_attn(
    const unsigned short* __restrict__ qkv, const unsigned* __restrict__ packed,
    const int* __restrict__ rowptr, const unsigned short* __restrict__ pc,
    unsigned short* __restrict__ msgb, int N)
{
  const int n = blockIdx.x;
  const int j = threadIdx.x;
  const int h = j >> 4;
  const int beg = rowptr[n], end = rowptr[n + 1];
  const float qj = bf2f(qkv[n * 384 + j]);
  float m = -3.0e38f, l = 0.f, acc = 0.f;

  float k0 = 0.f, v0 = 0.f, b0 = 0.f;
  if (beg < end) {
    unsigned p = packed[beg];
    int s = p & 0x3FFFF, t = p >> 18;
    k0 = bf2f(qkv[s * 384 + 128 + j]);
    v0 = bf2f(qkv[s * 384 + 256 + j]);
    b0 = bf2f(pc[PC_EB + t * 8 + h]);
  }
  for (int i = beg; i < end; ++i) {
    float k1 = 0.f, v1 = 0.f, b1 = 0.f;
    if (i + 1 < end) {             // prefetch next edge's rows
      unsigned p = packed[i + 1];
      int s = p & 0x3FFFF, t = p >> 18;
      k1 = bf2f(qkv[s * 384 + 128 + j]);
      v1 = bf2f(qkv[s * 384 + 256 + j]);
      b1 = bf2f(pc[PC_EB + t * 8 + h]);
    }
    float prod = qj * k0;
    #pragma unroll
    for (int o = 8; o; o >>= 1) prod += __shfl_xor(prod, o);  // 16-lane head sum
    float sc = prod * 0.25f + b0;
    float mn = fmaxf(m, sc);
    float c = __expf(m - mn);
    float p = __expf(sc - mn);
    l = l * c + p;
    acc = acc * c + p * v0;
    m = mn;
    k0 = k1; v0 = v1; b0 = b1;
  }
  msgb[n * 128 + j] = f2bf(acc / (l + 1e-9f));
}

// ---------- msg @ wo + bo, residual -> x1 (f32) ----------
__global__ __launch_bounds__(256) void k_attn_out(
    const void* __restrict__ xin, const int* __restrict__ flag,
    const unsigned short* __restrict__ msgb,
    const unsigned short* __restrict__ pc, float* __restrict__ x1,
    int rpb, int N)
{
  __shared__ unsigned short wos[128 * 128];  // 32 KB
  __shared__ float ms[128 * 4];
  const int tid = threadIdx.x;
  for (int idx = tid; idx < 2048; idx += 256) {
    int i = idx >> 4, j8 = (idx & 15) << 3;
    *(uint4*)&wos[i * 128 + j8] = *(const uint4*)&pc[PC_WO + i * 128 + j8];
  }
  const int cp = tid & 63, rg = tid >> 6;
  const float b0 = bf2f(pc[PC_BO + 2 * cp]), b1 = bf2f(pc[PC_BO + 2 * cp + 1]);
  const int isf = flag[0];
  __syncthreads();

  int row0 = blockIdx.x * rpb;
  int row1 = min(row0 + rpb, N);
  for (int row = row0; row < row1; row += 4) {
    {
      int e = tid & 127, half = tid >> 7;
      #pragma unroll
      for (int kk = 0; kk < 2; ++kk) {
        int r = row + 2 * half + kk;
        ms[e * 4 + 2 * half + kk] = (r < row1) ? bf2f(msgb[r * 128 + e]) : 0.f;
      }
    }
    __syncthreads();
    {
      float a0 = b0, a1 = b1;
      #pragma unroll 8
      for (int i = 0; i < 128; ++i) {
        float m = ms[i * 4 + rg];
        unsigned w = *(const unsigned*)&wos[i * 128 + 2 * cp];
        a0 += m * bf2f((unsigned short)w);
        a1 += m * bf2f((unsigned short)(w >> 16));
      }
      int r = row + rg;
      if (r < row1) {
        float xr0, xr1;
        if (isf) {
          float2 xx = ((const float2*)xin)[(r * 128 + 2 * cp) >> 1];
          xr0 = xx.x; xr1 = xx.y;
        } else {
          unsigned xx = ((const unsigned*)xin)[(r * 128 + 2 * cp) >> 1];
          xr0 = bf2f((unsigned short)xx); xr1 = bf2f((unsigned short)(xx >> 16));
        }
        float2 o; o.x = xr0 + a0; o.y = xr1 + a1;
        ((float2*)x1)[(r * 128 + 2 * cp) >> 1] = o;
      }
    }
    __syncthreads();
  }
}

// ---------- FFN2: out = x1 + t @ w2 + b2 (dual-dtype out) ----------
__global__ __launch_bounds__(256) void k_ffn2(
    const float* __restrict__ x1, const unsigned short* __restrict__ t,
    const unsigned short* __restrict__ pc, const int* __restrict__ flag,
    void* __restrict__ out, int rpb, int N)
{
  __shared__ unsigned short w2s[256 * 128];  // 64 KB
  const int tid = threadIdx.x;
  for (int idx = tid; idx < 4096; idx += 256)
    *(uint4*)&w2s[idx * 8] = *(const uint4*)&pc[PC_W2 + idx * 8];
  const int cp = tid & 63, rg = tid >> 6;
  const float b0 = bf2f(pc[PC_B2F + 2 * cp]), b1 = bf2f(pc[PC_B2F + 2 * cp + 1]);
  const int isf = flag[0];
  __syncthreads();

  int row0 = blockIdx.x * rpb;
  int row1 = min(row0 + rpb, N);
  for (int row = row0; row < row1; row += 4) {
    int r = row + rg;
    int rr = min(r, N - 1);
    float a0 = b0, a1 = b1;
    #pragma unroll 4
    for (int i8 = 0; i8 < 256; i8 += 8) {
      uint4 tw = *(const uint4*)&t[rr * 256 + i8];
      unsigned tws[4] = {tw.x, tw.y, tw.z, tw.w};
      #pragma unroll
      for (int u = 0; u < 4; ++u) {
        int i = i8 + 2 * u;
        float t0 = bf2f((unsigned short)tws[u]);
        float t1 = bf2f((unsigned short)(tws[u] >> 16));
        unsigned w0 = *(const unsigned*)&w2s[i * 128 + 2 * cp];
        unsigned w1 = *(const unsigned*)&w2s[(i + 1) * 128 + 2 * cp];
        a0 += t0 * bf2f((unsigned short)w0) + t1 * bf2f((unsigned short)w1);
        a1 += t0 * bf2f((unsigned short)(w0 >> 16)) + t1 * bf2f((unsigned short)(w1 >> 16));
      }
    }
    if (r < row1) {
      float2 xv = ((const float2*)x1)[(r * 128 + 2 * cp) >> 1];
      float o0 = xv.x + a0, o1 = xv.y + a1;
      if (isf) {
        float2 o; o.x = o0; o.y = o1;
        ((float2*)out)[(r * 128 + 2 * cp) >> 1] = o;
      } else {
        *(unsigned*)&((unsigned short*)out)[r * 128 + 2 * cp] = packbf(o0, o1);
      }
    }
  }
}

// ---------- launch ----------
extern "C" void kernel_launch(void* const* d_in, const int* in_sizes, int n_in,
                              void* d_out, int out_size, void* d_ws, size_t ws_size,
                              hipStream_t stream)
{
  const void* x = d_in[0];
  const int* ei = (const int*)d_in[1];
  const int* et = (const int*)d_in[2];
  const int N = in_sizes[0] / 128;
  const int E = in_sizes[2];

  char* ws = (char*)d_ws;
  size_t off = 0;
  auto alloc = [&](size_t bytes) -> void* {
    void* p = ws + off; off += (bytes + 255) & ~(size_t)255; return p;
  };
  int* flag = (int*)alloc(4);
  unsigned short* pc = (unsigned short*)alloc((size_t)PC_TOT * 2);
  unsigned short* qkv = (unsigned short*)alloc((size_t)N * 384 * 2);  // x1 overlays
  unsigned short* t = (unsigned short*)alloc((size_t)N * 256 * 2);
  unsigned* packed = (unsigned*)alloc((size_t)E * 4);
  int* rowptr = (int*)alloc((size_t)(N + 1) * 4);
  unsigned short* msgb = (unsigned short*)alloc((size_t)N * 128 * 2);
  size_t zoff = off;
  int* deg  = (int*)alloc((size_t)N * 4);
  int* fill = (int*)alloc((size_t)N * 4);
  hipMemsetAsync(ws + zoff, 0, off - zoff, stream);

  float* x1 = (float*)qkv;

  k_detect<<<1, 256, 0, stream>>>((const unsigned*)x, flag);

  PP pp;
  for (int i = 0; i < 17; ++i) pp.p[i] = d_in[5 + i];
  k_convert<<<(PC_TOT + 255) / 256, 256, 0, stream>>>(pp, flag, pc);

  // QKV: 3 slices, RB=391 row-blocks
  {
    int RB = 391, rpb = ((N + RB - 1) / RB + 3) & ~3;
    k_ln_mv<<<RB * 3, 256, 0, stream>>>(x, 0, flag, pc,
        PC_G1, PC_B1, PC_WQ, 128, 16512, PC_BQ, 16512,
        qkv, 384, 0, 3, rpb, N);
  }

  // CSR build
  int eb = (E + 255) / 256;
  k_count<<<eb, 256, 0, stream>>>(ei, deg, E);
  k_scan<<<1, 1024, 0, stream>>>(deg, rowptr, N);
  k_scatter<<<eb, 256, 0, stream>>>(ei, et, rowptr, fill, packed, E);

  // fused attention (no atomics)
  k_node_attn<<<N, 128, 0, stream>>>(qkv, packed, rowptr, pc, msgb, N);

  {
    int RB = 500, rpb = ((N + RB - 1) / RB + 3) & ~3;
    k_attn_out<<<RB, 256, 0, stream>>>(x, flag, msgb, pc, x1, rpb, N);
    // FFN1: 2 slices of w1
    k_ln_mv<<<RB * 2, 256, 0, stream>>>(x1, 1, flag, pc,
        PC_G2, PC_B2, PC_W1, 256, 128, PC_B1F, 128,
        t, 256, 1, 2, rpb, N);
    k_ffn2<<<RB, 256, 0, stream>>>(x1, t, pc, flag, d_out, rpb, N);
  }
}

// Round 4
// 485.337 us; speedup vs baseline: 2.3786x; 1.8889x over previous
//
#include <hip/hip_runtime.h>
#include <hip/hip_bf16.h>

typedef short bf16x8 __attribute__((ext_vector_type(8)));
typedef float f32x4 __attribute__((ext_vector_type(4)));

// ---------- helpers ----------
static __device__ __forceinline__ float bf2f(unsigned short u) {
  return __uint_as_float(((unsigned)u) << 16);
}
static __device__ __forceinline__ unsigned short f2bf(float f) {
  unsigned u = __float_as_uint(f);
  u += 0x7fffu + ((u >> 16) & 1u);   // RNE
  return (unsigned short)(u >> 16);
}
static __device__ __forceinline__ float gelu_tanh(float a) {
  float t = tanhf(0.7978845608028654f * (a + 0.044715f * a * a * a));
  return 0.5f * a * (1.0f + t);
}

// param-block element offsets (bf16 canonical)
#define PC_G1   0
#define PC_B1   128
#define PC_WQ   256
#define PC_BQ   16640
#define PC_WK   16768
#define PC_BK   33152
#define PC_WV   33280
#define PC_BV   49664
#define PC_EB   49792
#define PC_WO   49824
#define PC_BO   66208
#define PC_G2   66336
#define PC_B2   66464
#define PC_W1   66592
#define PC_B1F  99360
#define PC_W2   99616
#define PC_B2F  132384
#define PC_TOT  132512

// ---------- dtype detect ----------
__global__ void k_detect(const unsigned* __restrict__ x, int* __restrict__ flag) {
  __shared__ int cnt;
  if (threadIdx.x == 0) cnt = 0;
  __syncthreads();
  int good = 0;
  for (int i = threadIdx.x; i < 1024; i += 256) {
    float v = fabsf(bf2f((unsigned short)(x[i] & 0xFFFFu)));
    good += (v >= 0.0009765625f && v <= 32.0f) ? 1 : 0;
  }
  atomicAdd(&cnt, good);
  __syncthreads();
  if (threadIdx.x == 0) flag[0] = (cnt < 512) ? 1 : 0;   // 1 => inputs are f32
}

// ---------- canonicalize params to bf16 ----------
struct PP { const void* p[17]; };
__global__ __launch_bounds__(256) void k_convert(
    PP pp, const int* __restrict__ flag, unsigned short* __restrict__ pc)
{
  const int offs[18] = {PC_G1,PC_B1,PC_WQ,PC_BQ,PC_WK,PC_BK,PC_WV,PC_BV,PC_EB,
                        PC_WO,PC_BO,PC_G2,PC_B2,PC_W1,PC_B1F,PC_W2,PC_B2F,PC_TOT};
  int i = blockIdx.x * 256 + threadIdx.x;
  if (i >= PC_TOT) return;
  int s = 0;
  while (i >= offs[s + 1]) ++s;
  int local = i - offs[s];
  if (flag[0])
    pc[i] = f2bf(((const float*)pp.p[s])[local]);
  else
    pc[i] = ((const unsigned short*)pp.p[s])[local];
}

// ---------- pack weight matrix into MFMA B-fragment order ----------
// frag layout: dst[(((nt0+ntl)*(K/32)+ks)*64+lane)*8 + j] = W[ks*32+q*8+j][ntl*16+m]
__global__ __launch_bounds__(256) void k_pack(
    const unsigned short* __restrict__ pc, int w_off, int rs, int K, int ntl_n,
    unsigned short* __restrict__ dst, int nt0)
{
  int idx = blockIdx.x * 256 + threadIdx.x;
  int k32 = K >> 5;
  int total = ntl_n * k32 * 64;
  if (idx >= total) return;
  int lane = idx & 63;
  int ks = (idx >> 6) % k32;
  int ntl = idx / (64 * k32);
  int m = lane & 15, q = lane >> 4;
  int col = ntl * 16 + m;
  int kb = ks * 32 + q * 8;
  unsigned short tmp[8];
  #pragma unroll
  for (int j = 0; j < 8; ++j) tmp[j] = pc[w_off + (kb + j) * rs + col];
  *(uint4*)&dst[(size_t)(((nt0 + ntl) * k32 + ks) * 64 + lane) * 8] = *(const uint4*)tmp;
}

__global__ void k_bqkv(const unsigned short* __restrict__ pc, unsigned short* __restrict__ b) {
  int i = threadIdx.x;
  if (i >= 384) return;
  int s = i >> 7, c = i & 127;
  int off = (s == 0) ? PC_BQ : ((s == 1) ? PC_BK : PC_BV);
  b[i] = pc[off + c];
}

// ---------- LN + GEMM via MFMA (QKV and FFN1) ----------
__global__ __launch_bounds__(256) void k_lnmfma(
    const void* __restrict__ xin, int xmode, const int* __restrict__ flag,
    const unsigned short* __restrict__ pc, int lng_off, int lnb_off,
    const unsigned short* __restrict__ bias,
    const unsigned short* __restrict__ wpack, int ntiles, int do_gelu,
    unsigned short* __restrict__ dst, int dstride, int N)
{
  __shared__ unsigned short H[64 * 136];   // stride 136: 16B-aligned rows, 2-way bank alias (free)
  const int tid = threadIdx.x;
  const int row0 = blockIdx.x * 64;
  const int isf = xmode ? 1 : flag[0];
  {
    const int rl = tid >> 2, c0 = (tid & 3) * 32;
    const int r = row0 + rl;
    float xv[32];
    if (r < N) {
      if (isf) {
        const float4* xp = (const float4*)((const float*)xin + (size_t)r * 128 + c0);
        #pragma unroll
        for (int u = 0; u < 8; ++u) {
          float4 f = xp[u];
          xv[u*4] = f.x; xv[u*4+1] = f.y; xv[u*4+2] = f.z; xv[u*4+3] = f.w;
        }
      } else {
        const uint4* xp = (const uint4*)((const unsigned short*)xin + (size_t)r * 128 + c0);
        #pragma unroll
        for (int u = 0; u < 4; ++u) {
          uint4 w = xp[u];
          unsigned ww[4] = {w.x, w.y, w.z, w.w};
          #pragma unroll
          for (int p = 0; p < 4; ++p) {
            xv[u*8 + 2*p]     = bf2f((unsigned short)ww[p]);
            xv[u*8 + 2*p + 1] = bf2f((unsigned short)(ww[p] >> 16));
          }
        }
      }
    } else {
      #pragma unroll
      for (int u = 0; u < 32; ++u) xv[u] = 0.f;
    }
    float s = 0.f, s2 = 0.f;
    #pragma unroll
    for (int u = 0; u < 32; ++u) { s += xv[u]; s2 += xv[u] * xv[u]; }
    s += __shfl_xor(s, 1); s2 += __shfl_xor(s2, 1);
    s += __shfl_xor(s, 2); s2 += __shfl_xor(s2, 2);
    float mean = s * (1.f / 128.f);
    float var  = fmaxf(s2 * (1.f / 128.f) - mean * mean, 0.f);
    float inv  = rsqrtf(var + 1e-5f);
    unsigned short hb[32];
    #pragma unroll
    for (int u = 0; u < 32; ++u) {
      int c = c0 + u;
      hb[u] = f2bf((xv[u] - mean) * inv * bf2f(pc[lng_off + c]) + bf2f(pc[lnb_off + c]));
    }
    uint4* hp = (uint4*)&H[rl * 136 + c0];
    #pragma unroll
    for (int u = 0; u < 4; ++u) hp[u] = ((const uint4*)hb)[u];
  }
  __syncthreads();

  const int wave = tid >> 6, lane = tid & 63;
  const int m = lane & 15, q = lane >> 4;
  bf16x8 afr[4];
  {
    const unsigned short* hrow = &H[(wave * 16 + m) * 136 + q * 8];
    #pragma unroll
    for (int ks = 0; ks < 4; ++ks) afr[ks] = *(const bf16x8*)&hrow[ks * 32];
  }
  const int rowb = row0 + wave * 16 + q * 4;
  for (int nt = 0; nt < ntiles; nt += 2) {
    const bf16x8* bp = (const bf16x8*)&wpack[(size_t)(nt * 4 * 64 + lane) * 8];
    f32x4 acc0 = {0.f, 0.f, 0.f, 0.f}, acc1 = {0.f, 0.f, 0.f, 0.f};
    #pragma unroll
    for (int ks = 0; ks < 4; ++ks) {
      acc0 = __builtin_amdgcn_mfma_f32_16x16x32_bf16(afr[ks], bp[ks * 64],       acc0, 0, 0, 0);
      acc1 = __builtin_amdgcn_mfma_f32_16x16x32_bf16(afr[ks], bp[(4 + ks) * 64], acc1, 0, 0, 0);
    }
    #pragma unroll
    for (int tt = 0; tt < 2; ++tt) {
      f32x4 a = tt ? acc1 : acc0;
      int col = (nt + tt) * 16 + m;
      float bv = bf2f(bias[col]);
      #pragma unroll
      for (int rr = 0; rr < 4; ++rr) {
        int row = rowb + rr;
        if (row < N) {
          float o = a[rr] + bv;
          if (do_gelu) o = gelu_tanh(o);
          dst[(size_t)row * dstride + col] = f2bf(o);
        }
      }
    }
  }
}

// ---------- CSR build ----------
__global__ __launch_bounds__(256) void k_count(
    const int* __restrict__ ei, int* __restrict__ deg, int E)
{
  int e = blockIdx.x * 256 + threadIdx.x;
  if (e < E) atomicAdd(&deg[ei[E + e]], 1);
}

__global__ __launch_bounds__(1024) void k_scan(
    const int* __restrict__ deg, int* __restrict__ rowptr, int N)
{
  __shared__ int wsum[16];
  __shared__ int carry_s;
  const int tid = threadIdx.x, lane = tid & 63, wv = tid >> 6;
  if (tid == 0) carry_s = 0;
  __syncthreads();
  for (int base = 0; base < N; base += 1024) {
    int i = base + tid;
    int v = (i < N) ? deg[i] : 0;
    int s = v;
    #pragma unroll
    for (int o = 1; o < 64; o <<= 1) { int t = __shfl_up(s, o); if (lane >= o) s += t; }
    if (lane == 63) wsum[wv] = s;
    int carry = carry_s;
    __syncthreads();
    if (tid < 16) {
      int ws = wsum[tid];
      #pragma unroll
      for (int o = 1; o < 16; o <<= 1) { int t = __shfl_up(ws, o); if (tid >= o) ws += t; }
      wsum[tid] = ws;
    }
    __syncthreads();
    int woff = wv ? wsum[wv - 1] : 0;
    if (i < N) rowptr[i] = carry + woff + s - v;
    if (tid == 0) carry_s = carry + wsum[15];
    __syncthreads();
  }
  if (threadIdx.x == 0) rowptr[N] = carry_s;
}

__global__ __launch_bounds__(256) void k_scatter(
    const int* __restrict__ ei, const int* __restrict__ et,
    const int* __restrict__ rowptr, int* __restrict__ fill,
    unsigned* __restrict__ packed, int E)
{
  int e = blockIdx.x * 256 + threadIdx.x;
  if (e >= E) return;
  int d = ei[E + e];
  int pos = rowptr[d] + atomicAdd(&fill[d], 1);
  packed[pos] = (unsigned)ei[e] | ((unsigned)et[e] << 18);
}

// ---------- fused per-node attention ----------
__global__ __launch_bounds__(128) void k_node_attn(
    const unsigned short* __restrict__ qkv, const unsigned* __restrict__ packed,
    const int* __restrict__ rowptr, const unsigned short* __restrict__ pc,
    unsigned short* __restrict__ msgb, int N)
{
  const int n = blockIdx.x;
  const int j = threadIdx.x;
  const int h = j >> 4;
  const int beg = rowptr[n], end = rowptr[n + 1];
  const float qj = bf2f(qkv[(size_t)n * 384 + j]);
  float m = -3.0e38f, l = 0.f, acc = 0.f;

  float k0 = 0.f, v0 = 0.f, b0 = 0.f;
  if (beg < end) {
    unsigned p = packed[beg];
    int s = p & 0x3FFFF, t = p >> 18;
    k0 = bf2f(qkv[(size_t)s * 384 + 128 + j]);
    v0 = bf2f(qkv[(size_t)s * 384 + 256 + j]);
    b0 = bf2f(pc[PC_EB + t * 8 + h]);
  }
  for (int i = beg; i < end; ++i) {
    float k1 = 0.f, v1 = 0.f, b1 = 0.f;
    if (i + 1 < end) {
      unsigned p = packed[i + 1];
      int s = p & 0x3FFFF, t = p >> 18;
      k1 = bf2f(qkv[(size_t)s * 384 + 128 + j]);
      v1 = bf2f(qkv[(size_t)s * 384 + 256 + j]);
      b1 = bf2f(pc[PC_EB + t * 8 + h]);
    }
    float prod = qj * k0;
    #pragma unroll
    for (int o = 8; o; o >>= 1) prod += __shfl_xor(prod, o);
    float sc = prod * 0.25f + b0;
    float mn = fmaxf(m, sc);
    float c = __expf(m - mn);
    float p = __expf(sc - mn);
    l = l * c + p;
    acc = acc * c + p * v0;
    m = mn;
    k0 = k1; v0 = v1; b0 = b1;
  }
  msgb[(size_t)n * 128 + j] = f2bf(acc / (l + 1e-9f));
}

// ---------- msg @ wo + bo + x -> x1 (f32), MFMA ----------
__global__ __launch_bounds__(256) void k_owo(
    const void* __restrict__ xin, const int* __restrict__ flag,
    const unsigned short* __restrict__ msgb,
    const unsigned short* __restrict__ wpack, const unsigned short* __restrict__ pc,
    float* __restrict__ x1, int N)
{
  const int tid = threadIdx.x, wave = tid >> 6, lane = tid & 63;
  const int m = lane & 15, q = lane >> 4;
  const int row0 = blockIdx.x * 64 + wave * 16;
  const int isf = flag[0];
  bf16x8 afr[4];
  {
    const unsigned short* ap = msgb + (size_t)min(row0 + m, N - 1) * 128 + q * 8;
    #pragma unroll
    for (int ks = 0; ks < 4; ++ks) afr[ks] = *(const bf16x8*)&ap[ks * 32];
  }
  const int rowb = row0 + q * 4;
  for (int nt = 0; nt < 8; nt += 2) {
    const bf16x8* bp = (const bf16x8*)&wpack[(size_t)(nt * 4 * 64 + lane) * 8];
    f32x4 acc0 = {0.f, 0.f, 0.f, 0.f}, acc1 = {0.f, 0.f, 0.f, 0.f};
    #pragma unroll
    for (int ks = 0; ks < 4; ++ks) {
      acc0 = __builtin_amdgcn_mfma_f32_16x16x32_bf16(afr[ks], bp[ks * 64],       acc0, 0, 0, 0);
      acc1 = __builtin_amdgcn_mfma_f32_16x16x32_bf16(afr[ks], bp[(4 + ks) * 64], acc1, 0, 0, 0);
    }
    #pragma unroll
    for (int tt = 0; tt < 2; ++tt) {
      f32x4 a = tt ? acc1 : acc0;
      int col = (nt + tt) * 16 + m;
      float bv = bf2f(pc[PC_BO + col]);
      #pragma unroll
      for (int rr = 0; rr < 4; ++rr) {
        int row = rowb + rr;
        if (row < N) {
          float xr = isf ? ((const float*)xin)[(size_t)row * 128 + col]
                         : bf2f(((const unsigned short*)xin)[(size_t)row * 128 + col]);
          x1[(size_t)row * 128 + col] = a[rr] + bv + xr;
        }
      }
    }
  }
}

// ---------- t @ w2 + b2 + x1 -> out (dual dtype), MFMA K=256 ----------
__global__ __launch_bounds__(256) void k_ffn2m(
    const float* __restrict__ x1, const unsigned short* __restrict__ t,
    const unsigned short* __restrict__ wpack, const unsigned short* __restrict__ pc,
    const int* __restrict__ flag, void* __restrict__ out, int N)
{
  const int tid = threadIdx.x, wave = tid >> 6, lane = tid & 63;
  const int m = lane & 15, q = lane >> 4;
  const int row0 = blockIdx.x * 64 + wave * 16;
  const int isf = flag[0];
  bf16x8 afr[8];
  {
    const unsigned short* ap = t + (size_t)min(row0 + m, N - 1) * 256 + q * 8;
    #pragma unroll
    for (int ks = 0; ks < 8; ++ks) afr[ks] = *(const bf16x8*)&ap[ks * 32];
  }
  const int rowb = row0 + q * 4;
  for (int nt = 0; nt < 8; nt += 2) {
    const bf16x8* bp = (const bf16x8*)&wpack[(size_t)(nt * 8 * 64 + lane) * 8];
    f32x4 acc0 = {0.f, 0.f, 0.f, 0.f}, acc1 = {0.f, 0.f, 0.f, 0.f};
    #pragma unroll
    for (int ks = 0; ks < 8; ++ks) {
      acc0 = __builtin_amdgcn_mfma_f32_16x16x32_bf16(afr[ks], bp[ks * 64],       acc0, 0, 0, 0);
      acc1 = __builtin_amdgcn_mfma_f32_16x16x32_bf16(afr[ks], bp[(8 + ks) * 64], acc1, 0, 0, 0);
    }
    #pragma unroll
    for (int tt = 0; tt < 2; ++tt) {
      f32x4 a = tt ? acc1 : acc0;
      int col = (nt + tt) * 16 + m;
      float bv = bf2f(pc[PC_B2F + col]);
      #pragma unroll
      for (int rr = 0; rr < 4; ++rr) {
        int row = rowb + rr;
        if (row < N) {
          float o = a[rr] + bv + x1[(size_t)row * 128 + col];
          if (isf) ((float*)out)[(size_t)row * 128 + col] = o;
          else     ((unsigned short*)out)[(size_t)row * 128 + col] = f2bf(o);
        }
      }
    }
  }
}

// ---------- launch ----------
extern "C" void kernel_launch(void* const* d_in, const int* in_sizes, int n_in,
                              void* d_out, int out_size, void* d_ws, size_t ws_size,
                              hipStream_t stream)
{
  const void* x = d_in[0];
  const int* ei = (const int*)d_in[1];
  const int* et = (const int*)d_in[2];
  const int N = in_sizes[0] / 128;
  const int E = in_sizes[2];

  char* ws = (char*)d_ws;
  size_t off = 0;
  auto alloc = [&](size_t bytes) -> void* {
    void* p = ws + off; off += (bytes + 255) & ~(size_t)255; return p;
  };
  int* flag = (int*)alloc(4);
  unsigned short* pc = (unsigned short*)alloc((size_t)PC_TOT * 2);
  unsigned short* qkv = (unsigned short*)alloc((size_t)N * 384 * 2);  // x1 (f32 N*128) overlays
  unsigned short* t = (unsigned short*)alloc((size_t)N * 256 * 2);
  unsigned* packed = (unsigned*)alloc((size_t)E * 4);
  int* rowptr = (int*)alloc((size_t)(N + 1) * 4);
  unsigned short* msgb = (unsigned short*)alloc((size_t)N * 128 * 2);
  unsigned short* wqkvp = (unsigned short*)alloc((size_t)128 * 384 * 2);
  unsigned short* wop   = (unsigned short*)alloc((size_t)128 * 128 * 2);
  unsigned short* w1p   = (unsigned short*)alloc((size_t)128 * 256 * 2);
  unsigned short* w2p   = (unsigned short*)alloc((size_t)256 * 128 * 2);
  unsigned short* bqkvb = (unsigned short*)alloc(384 * 2);
  size_t zoff = off;
  int* deg  = (int*)alloc((size_t)N * 4);
  int* fill = (int*)alloc((size_t)N * 4);
  hipMemsetAsync(ws + zoff, 0, off - zoff, stream);

  float* x1 = (float*)qkv;

  k_detect<<<1, 256, 0, stream>>>((const unsigned*)x, flag);

  PP pp;
  for (int i = 0; i < 17; ++i) pp.p[i] = d_in[5 + i];
  k_convert<<<(PC_TOT + 255) / 256, 256, 0, stream>>>(pp, flag, pc);

  // weight repack into MFMA B-fragment order
  k_pack<<<8, 256, 0, stream>>>(pc, PC_WQ, 128, 128, 8, wqkvp, 0);
  k_pack<<<8, 256, 0, stream>>>(pc, PC_WK, 128, 128, 8, wqkvp, 8);
  k_pack<<<8, 256, 0, stream>>>(pc, PC_WV, 128, 128, 8, wqkvp, 16);
  k_pack<<<8, 256, 0, stream>>>(pc, PC_WO, 128, 128, 8, wop, 0);
  k_pack<<<16, 256, 0, stream>>>(pc, PC_W1, 256, 128, 16, w1p, 0);
  k_pack<<<16, 256, 0, stream>>>(pc, PC_W2, 128, 256, 8, w2p, 0);
  k_bqkv<<<1, 384, 0, stream>>>(pc, bqkvb);

  const int NB = (N + 63) / 64;

  // LN1 + QKV (MFMA)
  k_lnmfma<<<NB, 256, 0, stream>>>(x, 0, flag, pc, PC_G1, PC_B1, bqkvb,
                                   wqkvp, 24, 0, qkv, 384, N);

  // CSR build
  int eb = (E + 255) / 256;
  k_count<<<eb, 256, 0, stream>>>(ei, deg, E);
  k_scan<<<1, 1024, 0, stream>>>(deg, rowptr, N);
  k_scatter<<<eb, 256, 0, stream>>>(ei, et, rowptr, fill, packed, E);

  // fused attention (no atomics)
  k_node_attn<<<N, 128, 0, stream>>>(qkv, packed, rowptr, pc, msgb, N);

  // WO + residual (MFMA) -> x1 (overlays qkv; qkv no longer needed)
  k_owo<<<NB, 256, 0, stream>>>(x, flag, msgb, wop, pc, x1, N);

  // LN2 + FFN1 + gelu (MFMA)
  k_lnmfma<<<NB, 256, 0, stream>>>(x1, 1, flag, pc, PC_G2, PC_B2, pc + PC_B1F,
                                   w1p, 16, 1, t, 256, N);

  // FFN2 + residual (MFMA)
  k_ffn2m<<<NB, 256, 0, stream>>>(x1, t, w2p, pc, flag, d_out, N);
}

// Round 5
// 392.898 us; speedup vs baseline: 2.9382x; 1.2353x over previous
//
#include <hip/hip_runtime.h>
#include <hip/hip_bf16.h>

typedef short bf16x8 __attribute__((ext_vector_type(8)));
typedef float f32x4 __attribute__((ext_vector_type(4)));

// ---------- helpers ----------
static __device__ __forceinline__ float bf2f(unsigned short u) {
  return __uint_as_float(((unsigned)u) << 16);
}
static __device__ __forceinline__ unsigned short f2bf(float f) {
  unsigned u = __float_as_uint(f);
  u += 0x7fffu + ((u >> 16) & 1u);   // RNE
  return (unsigned short)(u >> 16);
}
static __device__ __forceinline__ unsigned packbf(float a, float b) {
  return (unsigned)f2bf(a) | ((unsigned)f2bf(b) << 16);
}
static __device__ __forceinline__ float gelu_tanh(float a) {
  float t = tanhf(0.7978845608028654f * (a + 0.044715f * a * a * a));
  return 0.5f * a * (1.0f + t);
}

// param-block element offsets (bf16 canonical)
#define PC_G1   0
#define PC_B1   128
#define PC_WQ   256
#define PC_BQ   16640
#define PC_WK   16768
#define PC_BK   33152
#define PC_WV   33280
#define PC_BV   49664
#define PC_EB   49792
#define PC_WO   49824
#define PC_BO   66208
#define PC_G2   66336
#define PC_B2   66464
#define PC_W1   66592
#define PC_B1F  99360
#define PC_W2   99616
#define PC_B2F  132384
#define PC_TOT  132512

// ---------- dtype detect ----------
__global__ void k_detect(const unsigned* __restrict__ x, int* __restrict__ flag) {
  __shared__ int cnt;
  if (threadIdx.x == 0) cnt = 0;
  __syncthreads();
  int good = 0;
  for (int i = threadIdx.x; i < 1024; i += 256) {
    float v = fabsf(bf2f((unsigned short)(x[i] & 0xFFFFu)));
    good += (v >= 0.0009765625f && v <= 32.0f) ? 1 : 0;
  }
  atomicAdd(&cnt, good);
  __syncthreads();
  if (threadIdx.x == 0) flag[0] = (cnt < 512) ? 1 : 0;   // 1 => inputs are f32
}

// ---------- canonicalize params to bf16 ----------
struct PP { const void* p[17]; };
__global__ __launch_bounds__(256) void k_convert(
    PP pp, const int* __restrict__ flag, unsigned short* __restrict__ pc)
{
  const int offs[18] = {PC_G1,PC_B1,PC_WQ,PC_BQ,PC_WK,PC_BK,PC_WV,PC_BV,PC_EB,
                        PC_WO,PC_BO,PC_G2,PC_B2,PC_W1,PC_B1F,PC_W2,PC_B2F,PC_TOT};
  int i = blockIdx.x * 256 + threadIdx.x;
  if (i >= PC_TOT) return;
  int s = 0;
  while (i >= offs[s + 1]) ++s;
  int local = i - offs[s];
  if (flag[0])
    pc[i] = f2bf(((const float*)pp.p[s])[local]);
  else
    pc[i] = ((const unsigned short*)pp.p[s])[local];
}

// ---------- pack weight matrix into MFMA B-fragment order ----------
__global__ __launch_bounds__(256) void k_pack(
    const unsigned short* __restrict__ pc, int w_off, int rs, int K, int ntl_n,
    unsigned short* __restrict__ dst, int nt0)
{
  int idx = blockIdx.x * 256 + threadIdx.x;
  int k32 = K >> 5;
  int total = ntl_n * k32 * 64;
  if (idx >= total) return;
  int lane = idx & 63;
  int ks = (idx >> 6) % k32;
  int ntl = idx / (64 * k32);
  int m = lane & 15, q = lane >> 4;
  int col = ntl * 16 + m;
  int kb = ks * 32 + q * 8;
  unsigned short tmp[8];
  #pragma unroll
  for (int j = 0; j < 8; ++j) tmp[j] = pc[w_off + (kb + j) * rs + col];
  *(uint4*)&dst[(size_t)(((nt0 + ntl) * k32 + ks) * 64 + lane) * 8] = *(const uint4*)tmp;
}

__global__ void k_bqkv(const unsigned short* __restrict__ pc, unsigned short* __restrict__ b) {
  int i = threadIdx.x;
  if (i >= 384) return;
  int s = i >> 7, c = i & 127;
  int off = (s == 0) ? PC_BQ : ((s == 1) ? PC_BK : PC_BV);
  b[i] = pc[off + c];
}

// ---------- LN1 + QKV GEMM via MFMA ----------
__global__ __launch_bounds__(256) void k_lnmfma(
    const void* __restrict__ xin, const int* __restrict__ flag,
    const unsigned short* __restrict__ pc, int lng_off, int lnb_off,
    const unsigned short* __restrict__ bias,
    const unsigned short* __restrict__ wpack, int ntiles,
    unsigned short* __restrict__ dst, int dstride, int N)
{
  __shared__ unsigned short H[64 * 136];
  const int tid = threadIdx.x;
  const int row0 = blockIdx.x * 64;
  const int isf = flag[0];
  {
    const int rl = tid >> 2, c0 = (tid & 3) * 32;
    const int r = row0 + rl;
    float xv[32];
    if (r < N) {
      if (isf) {
        const float4* xp = (const float4*)((const float*)xin + (size_t)r * 128 + c0);
        #pragma unroll
        for (int u = 0; u < 8; ++u) {
          float4 f = xp[u];
          xv[u*4] = f.x; xv[u*4+1] = f.y; xv[u*4+2] = f.z; xv[u*4+3] = f.w;
        }
      } else {
        const uint4* xp = (const uint4*)((const unsigned short*)xin + (size_t)r * 128 + c0);
        #pragma unroll
        for (int u = 0; u < 4; ++u) {
          uint4 w = xp[u];
          unsigned ww[4] = {w.x, w.y, w.z, w.w};
          #pragma unroll
          for (int p = 0; p < 4; ++p) {
            xv[u*8 + 2*p]     = bf2f((unsigned short)ww[p]);
            xv[u*8 + 2*p + 1] = bf2f((unsigned short)(ww[p] >> 16));
          }
        }
      }
    } else {
      #pragma unroll
      for (int u = 0; u < 32; ++u) xv[u] = 0.f;
    }
    float s = 0.f, s2 = 0.f;
    #pragma unroll
    for (int u = 0; u < 32; ++u) { s += xv[u]; s2 += xv[u] * xv[u]; }
    s += __shfl_xor(s, 1); s2 += __shfl_xor(s2, 1);
    s += __shfl_xor(s, 2); s2 += __shfl_xor(s2, 2);
    float mean = s * (1.f / 128.f);
    float var  = fmaxf(s2 * (1.f / 128.f) - mean * mean, 0.f);
    float inv  = rsqrtf(var + 1e-5f);
    unsigned short hb[32];
    #pragma unroll
    for (int u = 0; u < 32; ++u) {
      int c = c0 + u;
      hb[u] = f2bf((xv[u] - mean) * inv * bf2f(pc[lng_off + c]) + bf2f(pc[lnb_off + c]));
    }
    uint4* hp = (uint4*)&H[rl * 136 + c0];
    #pragma unroll
    for (int u = 0; u < 4; ++u) hp[u] = ((const uint4*)hb)[u];
  }
  __syncthreads();

  const int wave = tid >> 6, lane = tid & 63;
  const int m = lane & 15, q = lane >> 4;
  bf16x8 afr[4];
  {
    const unsigned short* hrow = &H[(wave * 16 + m) * 136 + q * 8];
    #pragma unroll
    for (int ks = 0; ks < 4; ++ks) afr[ks] = *(const bf16x8*)&hrow[ks * 32];
  }
  const int rowb = row0 + wave * 16 + q * 4;
  for (int nt = 0; nt < ntiles; nt += 2) {
    const bf16x8* bp = (const bf16x8*)&wpack[(size_t)(nt * 4 * 64 + lane) * 8];
    f32x4 acc0 = {0.f, 0.f, 0.f, 0.f}, acc1 = {0.f, 0.f, 0.f, 0.f};
    #pragma unroll
    for (int ks = 0; ks < 4; ++ks) {
      acc0 = __builtin_amdgcn_mfma_f32_16x16x32_bf16(afr[ks], bp[ks * 64],       acc0, 0, 0, 0);
      acc1 = __builtin_amdgcn_mfma_f32_16x16x32_bf16(afr[ks], bp[(4 + ks) * 64], acc1, 0, 0, 0);
    }
    #pragma unroll
    for (int tt = 0; tt < 2; ++tt) {
      f32x4 a = tt ? acc1 : acc0;
      int col = (nt + tt) * 16 + m;
      float bv = bf2f(bias[col]);
      #pragma unroll
      for (int rr = 0; rr < 4; ++rr) {
        int row = rowb + rr;
        if (row < N) dst[(size_t)row * dstride + col] = f2bf(a[rr] + bv);
      }
    }
  }
}

// ---------- CSR build ----------
__global__ __launch_bounds__(256) void k_count(
    const int* __restrict__ ei, int* __restrict__ deg, int E)
{
  int e = blockIdx.x * 256 + threadIdx.x;
  if (e < E) atomicAdd(&deg[ei[E + e]], 1);
}

__global__ __launch_bounds__(256) void k_scan1(
    const int* __restrict__ deg, int* __restrict__ rowptr,
    int* __restrict__ bsum, int N)
{
  __shared__ int ws[4];
  const int tid = threadIdx.x, lane = tid & 63, wv = tid >> 6;
  int i = blockIdx.x * 256 + tid;
  int v = (i < N) ? deg[i] : 0;
  int s = v;
  #pragma unroll
  for (int o = 1; o < 64; o <<= 1) { int t = __shfl_up(s, o); if (lane >= o) s += t; }
  if (lane == 63) ws[wv] = s;
  __syncthreads();
  int off = 0;
  for (int k = 0; k < wv; ++k) off += ws[k];
  if (i < N) rowptr[i] = off + s - v;
  if (tid == 255) bsum[blockIdx.x] = off + s;
}

__global__ __launch_bounds__(256) void k_scan2(
    int* __restrict__ bsum, int* __restrict__ rowptr, int M, int N)
{
  __shared__ int ws[4];
  __shared__ int carry_s;
  const int tid = threadIdx.x, lane = tid & 63, wv = tid >> 6;
  if (tid == 0) carry_s = 0;
  __syncthreads();
  for (int base = 0; base < M; base += 256) {
    int i = base + tid;
    int v = (i < M) ? bsum[i] : 0;
    int s = v;
    #pragma unroll
    for (int o = 1; o < 64; o <<= 1) { int t = __shfl_up(s, o); if (lane >= o) s += t; }
    if (lane == 63) ws[wv] = s;
    int c = carry_s;
    __syncthreads();
    int off = c;
    for (int k = 0; k < wv; ++k) off += ws[k];
    if (i < M) bsum[i] = off + s - v;
    __syncthreads();
    if (tid == 0) carry_s = c + ws[0] + ws[1] + ws[2] + ws[3];
    __syncthreads();
  }
  if (tid == 0) rowptr[N] = carry_s;
}

__global__ __launch_bounds__(256) void k_scan3(
    int* __restrict__ rowptr, const int* __restrict__ bsum, int N)
{
  int i = blockIdx.x * 256 + threadIdx.x;
  if (i < N) rowptr[i] += bsum[blockIdx.x];
}

__global__ __launch_bounds__(256) void k_scatter(
    const int* __restrict__ ei, const int* __restrict__ et,
    const int* __restrict__ rowptr, int* __restrict__ fill,
    unsigned* __restrict__ packed, int E)
{
  int e = blockIdx.x * 256 + threadIdx.x;
  if (e >= E) return;
  int d = ei[E + e];
  int pos = rowptr[d] + atomicAdd(&fill[d], 1);
  packed[pos] = (unsigned)ei[e] | ((unsigned)et[e] << 18);
}

// ---------- fused per-node attention: no-max softmax, wave-split edges ----------
__global__ __launch_bounds__(128) void k_node_attn(
    const unsigned short* __restrict__ qkv, const unsigned* __restrict__ packed,
    const int* __restrict__ rowptr, const unsigned short* __restrict__ pc,
    unsigned short* __restrict__ msgb, int N)
{
  __shared__ float ebs[32];
  __shared__ float red[192];
  const int n = blockIdx.x;
  const int tid = threadIdx.x, wave = tid >> 6, lane = tid & 63;
  if (tid < 32) ebs[tid] = bf2f(pc[PC_EB + tid]);
  const int h = lane >> 3;           // lane pair covers dims 2l,2l+1 -> head l>>3
  unsigned qw = *(const unsigned*)&qkv[(size_t)n * 384 + 2 * lane];
  float q0 = bf2f((unsigned short)qw), q1 = bf2f((unsigned short)(qw >> 16));
  const int beg = rowptr[n], end = rowptr[n + 1];
  float l = 0.f, a0 = 0.f, a1 = 0.f;
  __syncthreads();
  for (int i = beg + wave; i < end; i += 2) {
    unsigned p = packed[i];
    int s = p & 0x3FFFF, t = p >> 18;
    unsigned kw = *(const unsigned*)&qkv[(size_t)s * 384 + 128 + 2 * lane];
    unsigned vw = *(const unsigned*)&qkv[(size_t)s * 384 + 256 + 2 * lane];
    float prod = q0 * bf2f((unsigned short)kw) + q1 * bf2f((unsigned short)(kw >> 16));
    prod += __shfl_xor(prod, 1);
    prod += __shfl_xor(prod, 2);
    prod += __shfl_xor(prod, 4);
    float sc = fminf(prod * 0.25f + ebs[t * 8 + h], 80.f);  // scores tiny; clamp is a hedge
    float pe = __expf(sc);
    l += pe;
    a0 += pe * bf2f((unsigned short)vw);
    a1 += pe * bf2f((unsigned short)(vw >> 16));
  }
  if (wave == 1) { red[lane] = l; red[64 + lane] = a0; red[128 + lane] = a1; }
  __syncthreads();
  if (wave == 0) {
    l  += red[lane];
    a0 += red[64 + lane];
    a1 += red[128 + lane];
    float inv = 1.f / (l + 1e-9f);
    *(unsigned*)&msgb[(size_t)n * 128 + 2 * lane] = packbf(a0 * inv, a1 * inv);
  }
}

// ---------- fused tail: msg@wo+res -> LN2 -> FFN1(gelu) -> FFN2+res -> out ----------
__global__ __launch_bounds__(256) void k_tail(
    const void* __restrict__ xin, const int* __restrict__ flag,
    const unsigned short* __restrict__ msgb,
    const unsigned short* __restrict__ wop, const unsigned short* __restrict__ w1p,
    const unsigned short* __restrict__ w2p, const unsigned short* __restrict__ pc,
    void* __restrict__ out, int N)
{
  __shared__ unsigned short x1s[64 * 136];   // 17.4 KB  (x + attn residual, bf16)
  __shared__ unsigned short H[64 * 136];     // 17.4 KB  (LN2 output)
  __shared__ unsigned short ts[64 * 264];    // 33.8 KB  (FFN hidden)
  const int tid = threadIdx.x;
  const int row0 = blockIdx.x * 64;
  const int isf = flag[0];
  const int wave = tid >> 6, lane = tid & 63;
  const int m = lane & 15, q = lane >> 4;
  const int rowb = wave * 16 + q * 4;        // local row base for C tiles

  // pre-stage: x -> x1s (bf16)
  {
    int rl = tid >> 2, c0 = (tid & 3) * 32;
    int r = row0 + rl;
    unsigned short hb[32];
    if (r < N) {
      if (isf) {
        const float4* xp = (const float4*)((const float*)xin + (size_t)r * 128 + c0);
        #pragma unroll
        for (int u = 0; u < 8; ++u) {
          float4 f = xp[u];
          hb[u*4] = f2bf(f.x); hb[u*4+1] = f2bf(f.y);
          hb[u*4+2] = f2bf(f.z); hb[u*4+3] = f2bf(f.w);
        }
      } else {
        const uint4* xp = (const uint4*)((const unsigned short*)xin + (size_t)r * 128 + c0);
        #pragma unroll
        for (int u = 0; u < 4; ++u) ((uint4*)hb)[u] = xp[u];
      }
    } else {
      #pragma unroll
      for (int u = 0; u < 32; ++u) hb[u] = 0;
    }
    #pragma unroll
    for (int u = 0; u < 4; ++u) ((uint4*)&x1s[rl * 136 + c0])[u] = ((const uint4*)hb)[u];
  }
  // A-frags for stage 1 from msgb (global; independent of LDS)
  bf16x8 afr[4];
  {
    const unsigned short* ap = msgb + (size_t)min(row0 + wave * 16 + m, N - 1) * 128 + q * 8;
    #pragma unroll
    for (int ks = 0; ks < 4; ++ks) afr[ks] = *(const bf16x8*)&ap[ks * 32];
  }
  __syncthreads();

  // stage 1: x1 = x + msg@wo + bo   (RMW x1s, same-thread per element)
  for (int nt = 0; nt < 8; nt += 2) {
    const bf16x8* bp = (const bf16x8*)&wop[(size_t)(nt * 4 * 64 + lane) * 8];
    f32x4 acc0 = {0.f, 0.f, 0.f, 0.f}, acc1 = {0.f, 0.f, 0.f, 0.f};
    #pragma unroll
    for (int ks = 0; ks < 4; ++ks) {
      acc0 = __builtin_amdgcn_mfma_f32_16x16x32_bf16(afr[ks], bp[ks * 64],       acc0, 0, 0, 0);
      acc1 = __builtin_amdgcn_mfma_f32_16x16x32_bf16(afr[ks], bp[(4 + ks) * 64], acc1, 0, 0, 0);
    }
    #pragma unroll
    for (int tt = 0; tt < 2; ++tt) {
      f32x4 a = tt ? acc1 : acc0;
      int col = (nt + tt) * 16 + m;
      float bv = bf2f(pc[PC_BO + col]);
      #pragma unroll
      for (int rr = 0; rr < 4; ++rr) {
        int rl = rowb + rr;
        float o = a[rr] + bv + bf2f(x1s[rl * 136 + col]);
        x1s[rl * 136 + col] = f2bf(o);
      }
    }
  }
  __syncthreads();

  // stage 2: LN2(x1s) -> H
  {
    int rl = tid >> 2, c0 = (tid & 3) * 32;
    unsigned short hb[32];
    #pragma unroll
    for (int u = 0; u < 4; ++u) ((uint4*)hb)[u] = *(const uint4*)&x1s[rl * 136 + c0 + u * 8];
    float xv[32];
    #pragma unroll
    for (int u = 0; u < 32; ++u) xv[u] = bf2f(hb[u]);
    float s = 0.f, s2 = 0.f;
    #pragma unroll
    for (int u = 0; u < 32; ++u) { s += xv[u]; s2 += xv[u] * xv[u]; }
    s += __shfl_xor(s, 1); s2 += __shfl_xor(s2, 1);
    s += __shfl_xor(s, 2); s2 += __shfl_xor(s2, 2);
    float mean = s * (1.f / 128.f);
    float var  = fmaxf(s2 * (1.f / 128.f) - mean * mean, 0.f);
    float inv  = rsqrtf(var + 1e-5f);
    #pragma unroll
    for (int u = 0; u < 32; ++u) {
      int c = c0 + u;
      hb[u] = f2bf((xv[u] - mean) * inv * bf2f(pc[PC_G2 + c]) + bf2f(pc[PC_B2 + c]));
    }
    #pragma unroll
    for (int u = 0; u < 4; ++u) ((uint4*)&H[rl * 136 + c0])[u] = ((const uint4*)hb)[u];
  }
  __syncthreads();

  // stage 3: FFN1: t = gelu(H @ w1 + b1)
  bf16x8 hf[4];
  {
    const unsigned short* hp = &H[(wave * 16 + m) * 136 + q * 8];
    #pragma unroll
    for (int ks = 0; ks < 4; ++ks) hf[ks] = *(const bf16x8*)&hp[ks * 32];
  }
  for (int nt = 0; nt < 16; nt += 2) {
    const bf16x8* bp = (const bf16x8*)&w1p[(size_t)(nt * 4 * 64 + lane) * 8];
    f32x4 acc0 = {0.f, 0.f, 0.f, 0.f}, acc1 = {0.f, 0.f, 0.f, 0.f};
    #pragma unroll
    for (int ks = 0; ks < 4; ++ks) {
      acc0 = __builtin_amdgcn_mfma_f32_16x16x32_bf16(hf[ks], bp[ks * 64],       acc0, 0, 0, 0);
      acc1 = __builtin_amdgcn_mfma_f32_16x16x32_bf16(hf[ks], bp[(4 + ks) * 64], acc1, 0, 0, 0);
    }
    #pragma unroll
    for (int tt = 0; tt < 2; ++tt) {
      f32x4 a = tt ? acc1 : acc0;
      int col = (nt + tt) * 16 + m;
      float bv = bf2f(pc[PC_B1F + col]);
      #pragma unroll
      for (int rr = 0; rr < 4; ++rr)
        ts[(rowb + rr) * 264 + col] = f2bf(gelu_tanh(a[rr] + bv));
    }
  }
  __syncthreads();

  // stage 4: out = x1 + t @ w2 + b2
  bf16x8 tf[8];
  {
    const unsigned short* tp = &ts[(wave * 16 + m) * 264 + q * 8];
    #pragma unroll
    for (int ks = 0; ks < 8; ++ks) tf[ks] = *(const bf16x8*)&tp[ks * 32];
  }
  for (int nt = 0; nt < 8; nt += 2) {
    const bf16x8* bp = (const bf16x8*)&w2p[(size_t)(nt * 8 * 64 + lane) * 8];
    f32x4 acc0 = {0.f, 0.f, 0.f, 0.f}, acc1 = {0.f, 0.f, 0.f, 0.f};
    #pragma unroll
    for (int ks = 0; ks < 8; ++ks) {
      acc0 = __builtin_amdgcn_mfma_f32_16x16x32_bf16(tf[ks], bp[ks * 64],       acc0, 0, 0, 0);
      acc1 = __builtin_amdgcn_mfma_f32_16x16x32_bf16(tf[ks], bp[(8 + ks) * 64], acc1, 0, 0, 0);
    }
    #pragma unroll
    for (int tt = 0; tt < 2; ++tt) {
      f32x4 a = tt ? acc1 : acc0;
      int col = (nt + tt) * 16 + m;
      float bv = bf2f(pc[PC_B2F + col]);
      #pragma unroll
      for (int rr = 0; rr < 4; ++rr) {
        int rl = rowb + rr;
        int row = row0 + rl;
        if (row < N) {
          float o = a[rr] + bv + bf2f(x1s[rl * 136 + col]);
          if (isf) ((float*)out)[(size_t)row * 128 + col] = o;
          else     ((unsigned short*)out)[(size_t)row * 128 + col] = f2bf(o);
        }
      }
    }
  }
}

// ---------- launch ----------
extern "C" void kernel_launch(void* const* d_in, const int* in_sizes, int n_in,
                              void* d_out, int out_size, void* d_ws, size_t ws_size,
                              hipStream_t stream)
{
  const void* x = d_in[0];
  const int* ei = (const int*)d_in[1];
  const int* et = (const int*)d_in[2];
  const int N = in_sizes[0] / 128;
  const int E = in_sizes[2];

  char* ws = (char*)d_ws;
  size_t off = 0;
  auto alloc = [&](size_t bytes) -> void* {
    void* p = ws + off; off += (bytes + 255) & ~(size_t)255; return p;
  };
  int* flag = (int*)alloc(4);
  unsigned short* pc = (unsigned short*)alloc((size_t)PC_TOT * 2);
  unsigned short* qkv = (unsigned short*)alloc((size_t)N * 384 * 2);
  unsigned* packed = (unsigned*)alloc((size_t)E * 4);
  int* rowptr = (int*)alloc((size_t)(N + 1) * 4);
  unsigned short* msgb = (unsigned short*)alloc((size_t)N * 128 * 2);
  unsigned short* wqkvp = (unsigned short*)alloc((size_t)128 * 384 * 2);
  unsigned short* wop   = (unsigned short*)alloc((size_t)128 * 128 * 2);
  unsigned short* w1p   = (unsigned short*)alloc((size_t)128 * 256 * 2);
  unsigned short* w2p   = (unsigned short*)alloc((size_t)256 * 128 * 2);
  unsigned short* bqkvb = (unsigned short*)alloc(384 * 2);
  const int SB = (N + 255) / 256;
  int* bsum = (int*)alloc((size_t)SB * 4);
  size_t zoff = off;
  int* deg  = (int*)alloc((size_t)N * 4);
  int* fill = (int*)alloc((size_t)N * 4);
  hipMemsetAsync(ws + zoff, 0, off - zoff, stream);

  k_detect<<<1, 256, 0, stream>>>((const unsigned*)x, flag);

  PP pp;
  for (int i = 0; i < 17; ++i) pp.p[i] = d_in[5 + i];
  k_convert<<<(PC_TOT + 255) / 256, 256, 0, stream>>>(pp, flag, pc);

  // weight repack into MFMA B-fragment order
  k_pack<<<8, 256, 0, stream>>>(pc, PC_WQ, 128, 128, 8, wqkvp, 0);
  k_pack<<<8, 256, 0, stream>>>(pc, PC_WK, 128, 128, 8, wqkvp, 8);
  k_pack<<<8, 256, 0, stream>>>(pc, PC_WV, 128, 128, 8, wqkvp, 16);
  k_pack<<<8, 256, 0, stream>>>(pc, PC_WO, 128, 128, 8, wop, 0);
  k_pack<<<16, 256, 0, stream>>>(pc, PC_W1, 256, 128, 16, w1p, 0);
  k_pack<<<16, 256, 0, stream>>>(pc, PC_W2, 128, 256, 8, w2p, 0);
  k_bqkv<<<1, 384, 0, stream>>>(pc, bqkvb);

  const int NB = (N + 63) / 64;

  // LN1 + QKV (MFMA)
  k_lnmfma<<<NB, 256, 0, stream>>>(x, flag, pc, PC_G1, PC_B1, bqkvb,
                                   wqkvp, 24, qkv, 384, N);

  // CSR build (multi-block scan)
  int eb = (E + 255) / 256;
  k_count<<<eb, 256, 0, stream>>>(ei, deg, E);
  k_scan1<<<SB, 256, 0, stream>>>(deg, rowptr, bsum, N);
  k_scan2<<<1, 256, 0, stream>>>(bsum, rowptr, SB, N);
  k_scan3<<<SB, 256, 0, stream>>>(rowptr, bsum, N);
  k_scatter<<<eb, 256, 0, stream>>>(ei, et, rowptr, fill, packed, E);

  // fused attention (no atomics, no max pass)
  k_node_attn<<<N, 128, 0, stream>>>(qkv, packed, rowptr, pc, msgb, N);

  // fused tail: wo+residual, LN2, FFN1+gelu, FFN2+residual
  k_tail<<<NB, 256, 0, stream>>>(x, flag, msgb, wop, w1p, w2p, pc, d_out, N);
}

// Round 6
// 363.448 us; speedup vs baseline: 3.1763x; 1.0810x over previous
//
#include <hip/hip_runtime.h>
#include <hip/hip_bf16.h>

typedef short bf16x8 __attribute__((ext_vector_type(8)));
typedef float f32x4 __attribute__((ext_vector_type(4)));

// ---------- helpers ----------
static __device__ __forceinline__ float bf2f(unsigned short u) {
  return __uint_as_float(((unsigned)u) << 16);
}
static __device__ __forceinline__ unsigned short f2bf(float f) {
  unsigned u = __float_as_uint(f);
  u += 0x7fffu + ((u >> 16) & 1u);   // RNE
  return (unsigned short)(u >> 16);
}
static __device__ __forceinline__ unsigned packbf(float a, float b) {
  return (unsigned)f2bf(a) | ((unsigned)f2bf(b) << 16);
}
static __device__ __forceinline__ float gelu_tanh(float a) {
  float t = tanhf(0.7978845608028654f * (a + 0.044715f * a * a * a));
  return 0.5f * a * (1.0f + t);
}

// param-block element offsets (bf16 canonical)
#define PC_G1   0
#define PC_B1   128
#define PC_WQ   256
#define PC_BQ   16640
#define PC_WK   16768
#define PC_BK   33152
#define PC_WV   33280
#define PC_BV   49664
#define PC_EB   49792
#define PC_WO   49824
#define PC_BO   66208
#define PC_G2   66336
#define PC_B2   66464
#define PC_W1   66592
#define PC_B1F  99360
#define PC_W2   99616
#define PC_B2F  132384
#define PC_TOT  132512
#define B_CONV  518   // ceil(PC_TOT/256)

// ---------- dtype detect ----------
__global__ void k_detect(const unsigned* __restrict__ x, int* __restrict__ flag) {
  __shared__ int cnt;
  if (threadIdx.x == 0) cnt = 0;
  __syncthreads();
  int good = 0;
  for (int i = threadIdx.x; i < 1024; i += 256) {
    float v = fabsf(bf2f((unsigned short)(x[i] & 0xFFFFu)));
    good += (v >= 0.0009765625f && v <= 32.0f) ? 1 : 0;
  }
  atomicAdd(&cnt, good);
  __syncthreads();
  if (threadIdx.x == 0) flag[0] = (cnt < 512) ? 1 : 0;   // 1 => inputs are f32
}

// ---------- one-shot prep: convert params + repack weights + qkv bias ----------
struct PP { const void* p[17]; };

static __device__ __forceinline__ unsigned short rdw(const void* p, int isf, int idx) {
  return isf ? f2bf(((const float*)p)[idx]) : ((const unsigned short*)p)[idx];
}
static __device__ __forceinline__ void pack_one(
    const void* w, int isf, int rs, int K, int ntl_n,
    unsigned short* __restrict__ dst, int nt0, int idx)
{
  int k32 = K >> 5;
  if (idx >= ntl_n * k32 * 64) return;
  int lane = idx & 63;
  int ks = (idx >> 6) % k32;
  int ntl = idx / (64 * k32);
  int m = lane & 15, q = lane >> 4;
  int col = ntl * 16 + m;
  int kb = ks * 32 + q * 8;
  unsigned short tmp[8];
  #pragma unroll
  for (int j = 0; j < 8; ++j) tmp[j] = rdw(w, isf, (kb + j) * rs + col);
  *(uint4*)&dst[(size_t)(((nt0 + ntl) * k32 + ks) * 64 + lane) * 8] = *(const uint4*)tmp;
}

__global__ __launch_bounds__(256) void k_prep(
    PP pp, const int* __restrict__ flag, unsigned short* __restrict__ pc,
    unsigned short* __restrict__ wqkvp, unsigned short* __restrict__ wop,
    unsigned short* __restrict__ w1p, unsigned short* __restrict__ w2p,
    unsigned short* __restrict__ bqkvb)
{
  const int isf = flag[0];
  const int b = blockIdx.x, tid = threadIdx.x;
  if (b < B_CONV) {
    const int offs[18] = {PC_G1,PC_B1,PC_WQ,PC_BQ,PC_WK,PC_BK,PC_WV,PC_BV,PC_EB,
                          PC_WO,PC_BO,PC_G2,PC_B2,PC_W1,PC_B1F,PC_W2,PC_B2F,PC_TOT};
    int i = b * 256 + tid;
    if (i >= PC_TOT) return;
    int s = 0;
    while (i >= offs[s + 1]) ++s;
    pc[i] = rdw(pp.p[s], isf, i - offs[s]);
  } else if (b < B_CONV + 8)  pack_one(pp.p[2],  isf, 128, 128, 8,  wqkvp, 0,  (b - B_CONV) * 256 + tid);
  else if (b < B_CONV + 16)   pack_one(pp.p[4],  isf, 128, 128, 8,  wqkvp, 8,  (b - B_CONV - 8) * 256 + tid);
  else if (b < B_CONV + 24)   pack_one(pp.p[6],  isf, 128, 128, 8,  wqkvp, 16, (b - B_CONV - 16) * 256 + tid);
  else if (b < B_CONV + 32)   pack_one(pp.p[9],  isf, 128, 128, 8,  wop,   0,  (b - B_CONV - 24) * 256 + tid);
  else if (b < B_CONV + 48)   pack_one(pp.p[13], isf, 256, 128, 16, w1p,   0,  (b - B_CONV - 32) * 256 + tid);
  else if (b < B_CONV + 64)   pack_one(pp.p[15], isf, 128, 256, 8,  w2p,   0,  (b - B_CONV - 48) * 256 + tid);
  else {
    int i = (b - B_CONV - 64) * 256 + tid;
    if (i < 384) {
      int s = i >> 7, c = i & 127;
      const void* src = (s == 0) ? pp.p[3] : ((s == 1) ? pp.p[5] : pp.p[7]);
      bqkvb[i] = rdw(src, isf, c);
    }
  }
}

// ---------- LN1 + QKV GEMM via MFMA -> qb (q) + kvb (kv interleaved) ----------
__global__ __launch_bounds__(256) void k_lnqkv(
    const void* __restrict__ xin, const int* __restrict__ flag,
    const unsigned short* __restrict__ pc,
    const unsigned short* __restrict__ bias,
    const unsigned short* __restrict__ wpack,
    unsigned short* __restrict__ qb, unsigned short* __restrict__ kvb, int N)
{
  __shared__ unsigned short H[64 * 136];
  const int tid = threadIdx.x;
  const int row0 = blockIdx.x * 64;
  const int isf = flag[0];
  {
    const int rl = tid >> 2, c0 = (tid & 3) * 32;
    const int r = row0 + rl;
    float xv[32];
    if (r < N) {
      if (isf) {
        const float4* xp = (const float4*)((const float*)xin + (size_t)r * 128 + c0);
        #pragma unroll
        for (int u = 0; u < 8; ++u) {
          float4 f = xp[u];
          xv[u*4] = f.x; xv[u*4+1] = f.y; xv[u*4+2] = f.z; xv[u*4+3] = f.w;
        }
      } else {
        const uint4* xp = (const uint4*)((const unsigned short*)xin + (size_t)r * 128 + c0);
        #pragma unroll
        for (int u = 0; u < 4; ++u) {
          uint4 w = xp[u];
          unsigned ww[4] = {w.x, w.y, w.z, w.w};
          #pragma unroll
          for (int p = 0; p < 4; ++p) {
            xv[u*8 + 2*p]     = bf2f((unsigned short)ww[p]);
            xv[u*8 + 2*p + 1] = bf2f((unsigned short)(ww[p] >> 16));
          }
        }
      }
    } else {
      #pragma unroll
      for (int u = 0; u < 32; ++u) xv[u] = 0.f;
    }
    float s = 0.f, s2 = 0.f;
    #pragma unroll
    for (int u = 0; u < 32; ++u) { s += xv[u]; s2 += xv[u] * xv[u]; }
    s += __shfl_xor(s, 1); s2 += __shfl_xor(s2, 1);
    s += __shfl_xor(s, 2); s2 += __shfl_xor(s2, 2);
    float mean = s * (1.f / 128.f);
    float var  = fmaxf(s2 * (1.f / 128.f) - mean * mean, 0.f);
    float inv  = rsqrtf(var + 1e-5f);
    unsigned short hb[32];
    #pragma unroll
    for (int u = 0; u < 32; ++u) {
      int c = c0 + u;
      hb[u] = f2bf((xv[u] - mean) * inv * bf2f(pc[PC_G1 + c]) + bf2f(pc[PC_B1 + c]));
    }
    uint4* hp = (uint4*)&H[rl * 136 + c0];
    #pragma unroll
    for (int u = 0; u < 4; ++u) hp[u] = ((const uint4*)hb)[u];
  }
  __syncthreads();

  const int wave = tid >> 6, lane = tid & 63;
  const int m = lane & 15, q = lane >> 4;
  bf16x8 afr[4];
  {
    const unsigned short* hrow = &H[(wave * 16 + m) * 136 + q * 8];
    #pragma unroll
    for (int ks = 0; ks < 4; ++ks) afr[ks] = *(const bf16x8*)&hrow[ks * 32];
  }
  const int rowb = row0 + wave * 16 + q * 4;
  for (int nt = 0; nt < 24; nt += 2) {
    const bf16x8* bp = (const bf16x8*)&wpack[(size_t)(nt * 4 * 64 + lane) * 8];
    f32x4 acc0 = {0.f, 0.f, 0.f, 0.f}, acc1 = {0.f, 0.f, 0.f, 0.f};
    #pragma unroll
    for (int ks = 0; ks < 4; ++ks) {
      acc0 = __builtin_amdgcn_mfma_f32_16x16x32_bf16(afr[ks], bp[ks * 64],       acc0, 0, 0, 0);
      acc1 = __builtin_amdgcn_mfma_f32_16x16x32_bf16(afr[ks], bp[(4 + ks) * 64], acc1, 0, 0, 0);
    }
    #pragma unroll
    for (int tt = 0; tt < 2; ++tt) {
      f32x4 a = tt ? acc1 : acc0;
      int jj = (nt + tt) * 16 + m;
      float bv = bf2f(bias[jj]);
      #pragma unroll
      for (int rr = 0; rr < 4; ++rr) {
        int row = rowb + rr;
        if (row < N) {
          unsigned short val = f2bf(a[rr] + bv);
          if (jj < 128) {
            qb[(size_t)row * 128 + jj] = val;
          } else if (jj < 256) {
            int c = jj - 128;
            kvb[(size_t)row * 256 + ((c >> 1) << 2) + (c & 1)] = val;
          } else {
            int c = jj - 256;
            kvb[(size_t)row * 256 + ((c >> 1) << 2) + 2 + (c & 1)] = val;
          }
        }
      }
    }
  }
}

// ---------- CSR build ----------
__global__ __launch_bounds__(256) void k_count(
    const int* __restrict__ ei, int* __restrict__ deg, int E)
{
  int e = blockIdx.x * 256 + threadIdx.x;
  if (e < E) atomicAdd(&deg[ei[E + e]], 1);
}

__global__ __launch_bounds__(256) void k_scan1(
    const int* __restrict__ deg, int* __restrict__ rowptr,
    int* __restrict__ bsum, int N)
{
  __shared__ int ws[4];
  const int tid = threadIdx.x, lane = tid & 63, wv = tid >> 6;
  int i = blockIdx.x * 256 + tid;
  int v = (i < N) ? deg[i] : 0;
  int s = v;
  #pragma unroll
  for (int o = 1; o < 64; o <<= 1) { int t = __shfl_up(s, o); if (lane >= o) s += t; }
  if (lane == 63) ws[wv] = s;
  __syncthreads();
  int off = 0;
  for (int k = 0; k < wv; ++k) off += ws[k];
  if (i < N) rowptr[i] = off + s - v;
  if (tid == 255) bsum[blockIdx.x] = off + s;
}

__global__ __launch_bounds__(256) void k_scan2(
    int* __restrict__ bsum, int* __restrict__ rowptr, int M, int N)
{
  __shared__ int ws[4];
  __shared__ int carry_s;
  const int tid = threadIdx.x, lane = tid & 63, wv = tid >> 6;
  if (tid == 0) carry_s = 0;
  __syncthreads();
  for (int base = 0; base < M; base += 256) {
    int i = base + tid;
    int v = (i < M) ? bsum[i] : 0;
    int s = v;
    #pragma unroll
    for (int o = 1; o < 64; o <<= 1) { int t = __shfl_up(s, o); if (lane >= o) s += t; }
    if (lane == 63) ws[wv] = s;
    int c = carry_s;
    __syncthreads();
    int off = c;
    for (int k = 0; k < wv; ++k) off += ws[k];
    if (i < M) bsum[i] = off + s - v;
    __syncthreads();
    if (tid == 0) carry_s = c + ws[0] + ws[1] + ws[2] + ws[3];
    __syncthreads();
  }
  if (tid == 0) rowptr[N] = carry_s;
}

__global__ __launch_bounds__(256) void k_scan3(
    int* __restrict__ rowptr, const int* __restrict__ bsum, int N)
{
  int i = blockIdx.x * 256 + threadIdx.x;
  if (i < N) rowptr[i] += bsum[blockIdx.x];
}

__global__ __launch_bounds__(256) void k_scatter(
    const int* __restrict__ ei, const int* __restrict__ et,
    const int* __restrict__ rowptr, int* __restrict__ fill,
    unsigned* __restrict__ packed, int E)
{
  int e = blockIdx.x * 256 + threadIdx.x;
  if (e >= E) return;
  int d = ei[E + e];
  int pos = rowptr[d] + atomicAdd(&fill[d], 1);
  packed[pos] = (unsigned)ei[e] | ((unsigned)et[e] << 18);
}

// ---------- per-node attention: wave-per-node, 2-wide unroll, depth-2 prefetch ----------
__global__ __launch_bounds__(256) void k_attn(
    const unsigned short* __restrict__ qb, const unsigned short* __restrict__ kvb,
    const unsigned* __restrict__ packed, const int* __restrict__ rowptr,
    const unsigned short* __restrict__ pc, unsigned short* __restrict__ msgb,
    int N, int th)
{
  __shared__ float ebs[64];
  const int tid = threadIdx.x, lane = tid & 63, wave = tid >> 6;
  if (tid < th) ebs[tid] = bf2f(pc[PC_EB + tid]);
  __syncthreads();
  const int n = blockIdx.x * 4 + wave;
  if (n >= N) return;
  const int h = lane >> 3;   // 8 lanes (16 dims) per head
  unsigned qw = *(const unsigned*)&qb[(size_t)n * 128 + 2 * lane];
  float q0 = bf2f((unsigned short)qw), q1 = bf2f((unsigned short)(qw >> 16));
  const int beg = rowptr[n], end = rowptr[n + 1];
  float l = 0.f, a0 = 0.f, a1 = 0.f;
  if (beg < end) {
    int i1 = min(beg + 1, end - 1);
    unsigned pk0 = packed[beg], pk1 = packed[i1];
    uint2 kv0 = *(const uint2*)&kvb[(size_t)(pk0 & 0x3FFFF) * 256 + lane * 4];
    uint2 kv1 = *(const uint2*)&kvb[(size_t)(pk1 & 0x3FFFF) * 256 + lane * 4];
    for (int i = beg; i < end; i += 2) {
      int i2 = min(i + 2, end - 1), i3 = min(i + 3, end - 1);
      unsigned pk2 = packed[i2], pk3 = packed[i3];
      uint2 kv2 = *(const uint2*)&kvb[(size_t)(pk2 & 0x3FFFF) * 256 + lane * 4];
      uint2 kv3 = *(const uint2*)&kvb[(size_t)(pk3 & 0x3FFFF) * 256 + lane * 4];
      float p0 = q0 * bf2f((unsigned short)kv0.x) + q1 * bf2f((unsigned short)(kv0.x >> 16));
      float p1 = q0 * bf2f((unsigned short)kv1.x) + q1 * bf2f((unsigned short)(kv1.x >> 16));
      p0 += __shfl_xor(p0, 1);  p1 += __shfl_xor(p1, 1);
      p0 += __shfl_xor(p0, 2);  p1 += __shfl_xor(p1, 2);
      p0 += __shfl_xor(p0, 4);  p1 += __shfl_xor(p1, 4);
      float sc0 = p0 * 0.25f + ebs[(pk0 >> 18) * 8 + h];
      float sc1 = p1 * 0.25f + ebs[(pk1 >> 18) * 8 + h];
      float pe0 = __expf(fminf(sc0, 80.f));
      float pe1 = (i + 1 < end) ? __expf(fminf(sc1, 80.f)) : 0.f;
      l  += pe0 + pe1;
      a0 += pe0 * bf2f((unsigned short)kv0.y) + pe1 * bf2f((unsigned short)kv1.y);
      a1 += pe0 * bf2f((unsigned short)(kv0.y >> 16)) + pe1 * bf2f((unsigned short)(kv1.y >> 16));
      pk0 = pk2; pk1 = pk3; kv0 = kv2; kv1 = kv3;
    }
  }
  float inv = 1.f / (l + 1e-9f);
  *(unsigned*)&msgb[(size_t)n * 128 + 2 * lane] = packbf(a0 * inv, a1 * inv);
}

// ---------- fused tail: msg@wo+res -> LN2 -> FFN1(gelu) -> FFN2+res -> out ----------
__global__ __launch_bounds__(256) void k_tail(
    const void* __restrict__ xin, const int* __restrict__ flag,
    const unsigned short* __restrict__ msgb,
    const unsigned short* __restrict__ wop, const unsigned short* __restrict__ w1p,
    const unsigned short* __restrict__ w2p, const unsigned short* __restrict__ pc,
    void* __restrict__ out, int N)
{
  __shared__ unsigned short x1s[64 * 136];
  __shared__ unsigned short H[64 * 136];
  __shared__ unsigned short ts[64 * 264];
  const int tid = threadIdx.x;
  const int row0 = blockIdx.x * 64;
  const int isf = flag[0];
  const int wave = tid >> 6, lane = tid & 63;
  const int m = lane & 15, q = lane >> 4;
  const int rowb = wave * 16 + q * 4;

  {
    int rl = tid >> 2, c0 = (tid & 3) * 32;
    int r = row0 + rl;
    unsigned short hb[32];
    if (r < N) {
      if (isf) {
        const float4* xp = (const float4*)((const float*)xin + (size_t)r * 128 + c0);
        #pragma unroll
        for (int u = 0; u < 8; ++u) {
          float4 f = xp[u];
          hb[u*4] = f2bf(f.x); hb[u*4+1] = f2bf(f.y);
          hb[u*4+2] = f2bf(f.z); hb[u*4+3] = f2bf(f.w);
        }
      } else {
        const uint4* xp = (const uint4*)((const unsigned short*)xin + (size_t)r * 128 + c0);
        #pragma unroll
        for (int u = 0; u < 4; ++u) ((uint4*)hb)[u] = xp[u];
      }
    } else {
      #pragma unroll
      for (int u = 0; u < 32; ++u) hb[u] = 0;
    }
    #pragma unroll
    for (int u = 0; u < 4; ++u) ((uint4*)&x1s[rl * 136 + c0])[u] = ((const uint4*)hb)[u];
  }
  bf16x8 afr[4];
  {
    const unsigned short* ap = msgb + (size_t)min(row0 + wave * 16 + m, N - 1) * 128 + q * 8;
    #pragma unroll
    for (int ks = 0; ks < 4; ++ks) afr[ks] = *(const bf16x8*)&ap[ks * 32];
  }
  __syncthreads();

  for (int nt = 0; nt < 8; nt += 2) {
    const bf16x8* bp = (const bf16x8*)&wop[(size_t)(nt * 4 * 64 + lane) * 8];
    f32x4 acc0 = {0.f, 0.f, 0.f, 0.f}, acc1 = {0.f, 0.f, 0.f, 0.f};
    #pragma unroll
    for (int ks = 0; ks < 4; ++ks) {
      acc0 = __builtin_amdgcn_mfma_f32_16x16x32_bf16(afr[ks], bp[ks * 64],       acc0, 0, 0, 0);
      acc1 = __builtin_amdgcn_mfma_f32_16x16x32_bf16(afr[ks], bp[(4 + ks) * 64], acc1, 0, 0, 0);
    }
    #pragma unroll
    for (int tt = 0; tt < 2; ++tt) {
      f32x4 a = tt ? acc1 : acc0;
      int col = (nt + tt) * 16 + m;
      float bv = bf2f(pc[PC_BO + col]);
      #pragma unroll
      for (int rr = 0; rr < 4; ++rr) {
        int rl = rowb + rr;
        float o = a[rr] + bv + bf2f(x1s[rl * 136 + col]);
        x1s[rl * 136 + col] = f2bf(o);
      }
    }
  }
  __syncthreads();

  {
    int rl = tid >> 2, c0 = (tid & 3) * 32;
    unsigned short hb[32];
    #pragma unroll
    for (int u = 0; u < 4; ++u) ((uint4*)hb)[u] = *(const uint4*)&x1s[rl * 136 + c0 + u * 8];
    float xv[32];
    #pragma unroll
    for (int u = 0; u < 32; ++u) xv[u] = bf2f(hb[u]);
    float s = 0.f, s2 = 0.f;
    #pragma unroll
    for (int u = 0; u < 32; ++u) { s += xv[u]; s2 += xv[u] * xv[u]; }
    s += __shfl_xor(s, 1); s2 += __shfl_xor(s2, 1);
    s += __shfl_xor(s, 2); s2 += __shfl_xor(s2, 2);
    float mean = s * (1.f / 128.f);
    float var  = fmaxf(s2 * (1.f / 128.f) - mean * mean, 0.f);
    float inv  = rsqrtf(var + 1e-5f);
    #pragma unroll
    for (int u = 0; u < 32; ++u) {
      int c = c0 + u;
      hb[u] = f2bf((xv[u] - mean) * inv * bf2f(pc[PC_G2 + c]) + bf2f(pc[PC_B2 + c]));
    }
    #pragma unroll
    for (int u = 0; u < 4; ++u) ((uint4*)&H[rl * 136 + c0])[u] = ((const uint4*)hb)[u];
  }
  __syncthreads();

  bf16x8 hf[4];
  {
    const unsigned short* hp = &H[(wave * 16 + m) * 136 + q * 8];
    #pragma unroll
    for (int ks = 0; ks < 4; ++ks) hf[ks] = *(const bf16x8*)&hp[ks * 32];
  }
  for (int nt = 0; nt < 16; nt += 2) {
    const bf16x8* bp = (const bf16x8*)&w1p[(size_t)(nt * 4 * 64 + lane) * 8];
    f32x4 acc0 = {0.f, 0.f, 0.f, 0.f}, acc1 = {0.f, 0.f, 0.f, 0.f};
    #pragma unroll
    for (int ks = 0; ks < 4; ++ks) {
      acc0 = __builtin_amdgcn_mfma_f32_16x16x32_bf16(hf[ks], bp[ks * 64],       acc0, 0, 0, 0);
      acc1 = __builtin_amdgcn_mfma_f32_16x16x32_bf16(hf[ks], bp[(4 + ks) * 64], acc1, 0, 0, 0);
    }
    #pragma unroll
    for (int tt = 0; tt < 2; ++tt) {
      f32x4 a = tt ? acc1 : acc0;
      int col = (nt + tt) * 16 + m;
      float bv = bf2f(pc[PC_B1F + col]);
      #pragma unroll
      for (int rr = 0; rr < 4; ++rr)
        ts[(rowb + rr) * 264 + col] = f2bf(gelu_tanh(a[rr] + bv));
    }
  }
  __syncthreads();

  bf16x8 tf[8];
  {
    const unsigned short* tp = &ts[(wave * 16 + m) * 264 + q * 8];
    #pragma unroll
    for (int ks = 0; ks < 8; ++ks) tf[ks] = *(const bf16x8*)&tp[ks * 32];
  }
  for (int nt = 0; nt < 8; nt += 2) {
    const bf16x8* bp = (const bf16x8*)&w2p[(size_t)(nt * 8 * 64 + lane) * 8];
    f32x4 acc0 = {0.f, 0.f, 0.f, 0.f}, acc1 = {0.f, 0.f, 0.f, 0.f};
    #pragma unroll
    for (int ks = 0; ks < 8; ++ks) {
      acc0 = __builtin_amdgcn_mfma_f32_16x16x32_bf16(tf[ks], bp[ks * 64],       acc0, 0, 0, 0);
      acc1 = __builtin_amdgcn_mfma_f32_16x16x32_bf16(tf[ks], bp[(8 + ks) * 64], acc1, 0, 0, 0);
    }
    #pragma unroll
    for (int tt = 0; tt < 2; ++tt) {
      f32x4 a = tt ? acc1 : acc0;
      int col = (nt + tt) * 16 + m;
      float bv = bf2f(pc[PC_B2F + col]);
      #pragma unroll
      for (int rr = 0; rr < 4; ++rr) {
        int rl = rowb + rr;
        int row = row0 + rl;
        if (row < N) {
          float o = a[rr] + bv + bf2f(x1s[rl * 136 + col]);
          if (isf) ((float*)out)[(size_t)row * 128 + col] = o;
          else     ((unsigned short*)out)[(size_t)row * 128 + col] = f2bf(o);
        }
      }
    }
  }
}

// ---------- launch ----------
extern "C" void kernel_launch(void* const* d_in, const int* in_sizes, int n_in,
                              void* d_out, int out_size, void* d_ws, size_t ws_size,
                              hipStream_t stream)
{
  const void* x = d_in[0];
  const int* ei = (const int*)d_in[1];
  const int* et = (const int*)d_in[2];
  const int N = in_sizes[0] / 128;
  const int E = in_sizes[2];
  int th = in_sizes[13];
  if (th > 64) th = 64;

  char* ws = (char*)d_ws;
  size_t off = 0;
  auto alloc = [&](size_t bytes) -> void* {
    void* p = ws + off; off += (bytes + 255) & ~(size_t)255; return p;
  };
  int* flag = (int*)alloc(4);
  unsigned short* pc = (unsigned short*)alloc((size_t)PC_TOT * 2);
  unsigned short* qb  = (unsigned short*)alloc((size_t)N * 128 * 2);
  unsigned short* kvb = (unsigned short*)alloc((size_t)N * 256 * 2);
  unsigned* packed = (unsigned*)alloc((size_t)E * 4);
  int* rowptr = (int*)alloc((size_t)(N + 1) * 4);
  unsigned short* msgb = (unsigned short*)alloc((size_t)N * 128 * 2);
  unsigned short* wqkvp = (unsigned short*)alloc((size_t)128 * 384 * 2);
  unsigned short* wop   = (unsigned short*)alloc((size_t)128 * 128 * 2);
  unsigned short* w1p   = (unsigned short*)alloc((size_t)128 * 256 * 2);
  unsigned short* w2p   = (unsigned short*)alloc((size_t)256 * 128 * 2);
  unsigned short* bqkvb = (unsigned short*)alloc(384 * 2);
  const int SB = (N + 255) / 256;
  int* bsum = (int*)alloc((size_t)SB * 4);
  size_t zoff = off;
  int* deg  = (int*)alloc((size_t)N * 4);
  int* fill = (int*)alloc((size_t)N * 4);
  hipMemsetAsync(ws + zoff, 0, off - zoff, stream);

  k_detect<<<1, 256, 0, stream>>>((const unsigned*)x, flag);

  PP pp;
  for (int i = 0; i < 17; ++i) pp.p[i] = d_in[5 + i];
  k_prep<<<B_CONV + 66, 256, 0, stream>>>(pp, flag, pc, wqkvp, wop, w1p, w2p, bqkvb);

  const int NB = (N + 63) / 64;

  // LN1 + QKV (MFMA) -> qb, kvb(interleaved)
  k_lnqkv<<<NB, 256, 0, stream>>>(x, flag, pc, bqkvb, wqkvp, qb, kvb, N);

  // CSR build (multi-block scan)
  int eb = (E + 255) / 256;
  k_count<<<eb, 256, 0, stream>>>(ei, deg, E);
  k_scan1<<<SB, 256, 0, stream>>>(deg, rowptr, bsum, N);
  k_scan2<<<1, 256, 0, stream>>>(bsum, rowptr, SB, N);
  k_scan3<<<SB, 256, 0, stream>>>(rowptr, bsum, N);
  k_scatter<<<eb, 256, 0, stream>>>(ei, et, rowptr, fill, packed, E);

  // attention: wave-per-node, 4 nodes/block
  k_attn<<<(N + 3) / 4, 256, 0, stream>>>(qb, kvb, packed, rowptr, pc, msgb, N, th);

  // fused tail
  k_tail<<<NB, 256, 0, stream>>>(x, flag, msgb, wop, w1p, w2p, pc, d_out, N);
}

// Round 7
// 338.841 us; speedup vs baseline: 3.4070x; 1.0726x over previous
//
#include <hip/hip_runtime.h>
#include <hip/hip_bf16.h>

typedef short bf16x8 __attribute__((ext_vector_type(8)));
typedef float f32x4 __attribute__((ext_vector_type(4)));
typedef _Float16 f16x2 __attribute__((ext_vector_type(2)));
typedef _Float16 f16x8 __attribute__((ext_vector_type(8)));

// ---------- helpers ----------
static __device__ __forceinline__ float bf2f(unsigned short u) {
  return __uint_as_float(((unsigned)u) << 16);
}
static __device__ __forceinline__ unsigned short f2bf(float f) {
  unsigned u = __float_as_uint(f);
  u += 0x7fffu + ((u >> 16) & 1u);   // RNE
  return (unsigned short)(u >> 16);
}
static __device__ __forceinline__ unsigned packbf(float a, float b) {
  return (unsigned)f2bf(a) | ((unsigned)f2bf(b) << 16);
}
static __device__ __forceinline__ float gelu_tanh(float a) {
  float t = tanhf(0.7978845608028654f * (a + 0.044715f * a * a * a));
  return 0.5f * a * (1.0f + t);
}
static __device__ __forceinline__ float dot2(f16x2 a, f16x2 b, float c) {
#if __has_builtin(__builtin_amdgcn_fdot2)
  return __builtin_amdgcn_fdot2(a, b, c, false);
#else
  return c + (float)a[0] * (float)b[0] + (float)a[1] * (float)b[1];
#endif
}
template <typename T, typename F>
static __device__ __forceinline__ T bcast(F v) {
  union { F f; T t; } u; u.f = v; return u.t;
}

// param-block element offsets (bf16 canonical)
#define PC_G1   0
#define PC_B1   128
#define PC_WQ   256
#define PC_BQ   16640
#define PC_WK   16768
#define PC_BK   33152
#define PC_WV   33280
#define PC_BV   49664
#define PC_EB   49792
#define PC_WO   49824
#define PC_BO   66208
#define PC_G2   66336
#define PC_B2   66464
#define PC_W1   66592
#define PC_B1F  99360
#define PC_W2   99616
#define PC_B2F  132384
#define PC_TOT  132512
#define B_CONV  518   // ceil(PC_TOT/256)

// ---------- dtype detect ----------
__global__ void k_detect(const unsigned* __restrict__ x, int* __restrict__ flag) {
  __shared__ int cnt;
  if (threadIdx.x == 0) cnt = 0;
  __syncthreads();
  int good = 0;
  for (int i = threadIdx.x; i < 1024; i += 256) {
    float v = fabsf(bf2f((unsigned short)(x[i] & 0xFFFFu)));
    good += (v >= 0.0009765625f && v <= 32.0f) ? 1 : 0;
  }
  atomicAdd(&cnt, good);
  __syncthreads();
  if (threadIdx.x == 0) flag[0] = (cnt < 512) ? 1 : 0;   // 1 => inputs are f32
}

// ---------- one-shot prep: convert params + repack weights + qkv bias ----------
struct PP { const void* p[17]; };

static __device__ __forceinline__ unsigned short rdw(const void* p, int isf, int idx) {
  return isf ? f2bf(((const float*)p)[idx]) : ((const unsigned short*)p)[idx];
}
static __device__ __forceinline__ void pack_one(
    const void* w, int isf, int rs, int K, int ntl_n,
    unsigned short* __restrict__ dst, int nt0, int idx)
{
  int k32 = K >> 5;
  if (idx >= ntl_n * k32 * 64) return;
  int lane = idx & 63;
  int ks = (idx >> 6) % k32;
  int ntl = idx / (64 * k32);
  int m = lane & 15, q = lane >> 4;
  int col = ntl * 16 + m;
  int kb = ks * 32 + q * 8;
  unsigned short tmp[8];
  #pragma unroll
  for (int j = 0; j < 8; ++j) tmp[j] = rdw(w, isf, (kb + j) * rs + col);
  *(uint4*)&dst[(size_t)(((nt0 + ntl) * k32 + ks) * 64 + lane) * 8] = *(const uint4*)tmp;
}

__global__ __launch_bounds__(256) void k_prep(
    PP pp, const int* __restrict__ flag, unsigned short* __restrict__ pc,
    unsigned short* __restrict__ wqkvp, unsigned short* __restrict__ wop,
    unsigned short* __restrict__ w1p, unsigned short* __restrict__ w2p,
    unsigned short* __restrict__ bqkvb)
{
  const int isf = flag[0];
  const int b = blockIdx.x, tid = threadIdx.x;
  if (b < B_CONV) {
    const int offs[18] = {PC_G1,PC_B1,PC_WQ,PC_BQ,PC_WK,PC_BK,PC_WV,PC_BV,PC_EB,
                          PC_WO,PC_BO,PC_G2,PC_B2,PC_W1,PC_B1F,PC_W2,PC_B2F,PC_TOT};
    int i = b * 256 + tid;
    if (i >= PC_TOT) return;
    int s = 0;
    while (i >= offs[s + 1]) ++s;
    pc[i] = rdw(pp.p[s], isf, i - offs[s]);
  } else if (b < B_CONV + 8)  pack_one(pp.p[2],  isf, 128, 128, 8,  wqkvp, 0,  (b - B_CONV) * 256 + tid);
  else if (b < B_CONV + 16)   pack_one(pp.p[4],  isf, 128, 128, 8,  wqkvp, 8,  (b - B_CONV - 8) * 256 + tid);
  else if (b < B_CONV + 24)   pack_one(pp.p[6],  isf, 128, 128, 8,  wqkvp, 16, (b - B_CONV - 16) * 256 + tid);
  else if (b < B_CONV + 32)   pack_one(pp.p[9],  isf, 128, 128, 8,  wop,   0,  (b - B_CONV - 24) * 256 + tid);
  else if (b < B_CONV + 48)   pack_one(pp.p[13], isf, 256, 128, 16, w1p,   0,  (b - B_CONV - 32) * 256 + tid);
  else if (b < B_CONV + 64)   pack_one(pp.p[15], isf, 128, 256, 8,  w2p,   0,  (b - B_CONV - 48) * 256 + tid);
  else {
    int i = (b - B_CONV - 64) * 256 + tid;
    if (i < 384) {
      int s = i >> 7, c = i & 127;
      const void* src = (s == 0) ? pp.p[3] : ((s == 1) ? pp.p[5] : pp.p[7]);
      bqkvb[i] = rdw(src, isf, c);
    }
  }
}

// ---------- LN1 + QKV GEMM via MFMA -> qb (f16) + kvb (f16, [h][k16|v16]) ----------
__global__ __launch_bounds__(256) void k_lnqkv(
    const void* __restrict__ xin, const int* __restrict__ flag,
    const unsigned short* __restrict__ pc,
    const unsigned short* __restrict__ bias,
    const unsigned short* __restrict__ wpack,
    _Float16* __restrict__ qb, _Float16* __restrict__ kvb, int N)
{
  __shared__ unsigned short H[64 * 136];
  const int tid = threadIdx.x;
  const int row0 = blockIdx.x * 64;
  const int isf = flag[0];
  {
    const int rl = tid >> 2, c0 = (tid & 3) * 32;
    const int r = row0 + rl;
    float xv[32];
    if (r < N) {
      if (isf) {
        const float4* xp = (const float4*)((const float*)xin + (size_t)r * 128 + c0);
        #pragma unroll
        for (int u = 0; u < 8; ++u) {
          float4 f = xp[u];
          xv[u*4] = f.x; xv[u*4+1] = f.y; xv[u*4+2] = f.z; xv[u*4+3] = f.w;
        }
      } else {
        const uint4* xp = (const uint4*)((const unsigned short*)xin + (size_t)r * 128 + c0);
        #pragma unroll
        for (int u = 0; u < 4; ++u) {
          uint4 w = xp[u];
          unsigned ww[4] = {w.x, w.y, w.z, w.w};
          #pragma unroll
          for (int p = 0; p < 4; ++p) {
            xv[u*8 + 2*p]     = bf2f((unsigned short)ww[p]);
            xv[u*8 + 2*p + 1] = bf2f((unsigned short)(ww[p] >> 16));
          }
        }
      }
    } else {
      #pragma unroll
      for (int u = 0; u < 32; ++u) xv[u] = 0.f;
    }
    float s = 0.f, s2 = 0.f;
    #pragma unroll
    for (int u = 0; u < 32; ++u) { s += xv[u]; s2 += xv[u] * xv[u]; }
    s += __shfl_xor(s, 1); s2 += __shfl_xor(s2, 1);
    s += __shfl_xor(s, 2); s2 += __shfl_xor(s2, 2);
    float mean = s * (1.f / 128.f);
    float var  = fmaxf(s2 * (1.f / 128.f) - mean * mean, 0.f);
    float inv  = rsqrtf(var + 1e-5f);
    unsigned short hb[32];
    #pragma unroll
    for (int u = 0; u < 32; ++u) {
      int c = c0 + u;
      hb[u] = f2bf((xv[u] - mean) * inv * bf2f(pc[PC_G1 + c]) + bf2f(pc[PC_B1 + c]));
    }
    uint4* hp = (uint4*)&H[rl * 136 + c0];
    #pragma unroll
    for (int u = 0; u < 4; ++u) hp[u] = ((const uint4*)hb)[u];
  }
  __syncthreads();

  const int wave = tid >> 6, lane = tid & 63;
  const int m = lane & 15, q = lane >> 4;
  bf16x8 afr[4];
  {
    const unsigned short* hrow = &H[(wave * 16 + m) * 136 + q * 8];
    #pragma unroll
    for (int ks = 0; ks < 4; ++ks) afr[ks] = *(const bf16x8*)&hrow[ks * 32];
  }
  const int rowb = row0 + wave * 16 + q * 4;
  for (int nt = 0; nt < 24; nt += 2) {
    const bf16x8* bp = (const bf16x8*)&wpack[(size_t)(nt * 4 * 64 + lane) * 8];
    f32x4 acc0 = {0.f, 0.f, 0.f, 0.f}, acc1 = {0.f, 0.f, 0.f, 0.f};
    #pragma unroll
    for (int ks = 0; ks < 4; ++ks) {
      acc0 = __builtin_amdgcn_mfma_f32_16x16x32_bf16(afr[ks], bp[ks * 64],       acc0, 0, 0, 0);
      acc1 = __builtin_amdgcn_mfma_f32_16x16x32_bf16(afr[ks], bp[(4 + ks) * 64], acc1, 0, 0, 0);
    }
    #pragma unroll
    for (int tt = 0; tt < 2; ++tt) {
      f32x4 a = tt ? acc1 : acc0;
      int jj = (nt + tt) * 16 + m;
      float bv = bf2f(bias[jj]);
      #pragma unroll
      for (int rr = 0; rr < 4; ++rr) {
        int row = rowb + rr;
        if (row < N) {
          _Float16 hv = (_Float16)(a[rr] + bv);
          if (jj < 128) {
            qb[(size_t)row * 128 + jj] = hv;
          } else if (jj < 256) {
            int c = jj - 128;
            kvb[(size_t)row * 256 + (c >> 4) * 32 + (c & 15)] = hv;
          } else {
            int c = jj - 256;
            kvb[(size_t)row * 256 + (c >> 4) * 32 + 16 + (c & 15)] = hv;
          }
        }
      }
    }
  }
}

// ---------- CSR build ----------
__global__ __launch_bounds__(256) void k_count(
    const int* __restrict__ ei, int* __restrict__ deg, int E)
{
  int e = blockIdx.x * 256 + threadIdx.x;
  if (e < E) atomicAdd(&deg[ei[E + e]], 1);
}

__global__ __launch_bounds__(256) void k_scan1(
    const int* __restrict__ deg, int* __restrict__ rowptr,
    int* __restrict__ bsum, int N)
{
  __shared__ int ws[4];
  const int tid = threadIdx.x, lane = tid & 63, wv = tid >> 6;
  int i = blockIdx.x * 256 + tid;
  int v = (i < N) ? deg[i] : 0;
  int s = v;
  #pragma unroll
  for (int o = 1; o < 64; o <<= 1) { int t = __shfl_up(s, o); if (lane >= o) s += t; }
  if (lane == 63) ws[wv] = s;
  __syncthreads();
  int off = 0;
  for (int k = 0; k < wv; ++k) off += ws[k];
  if (i < N) rowptr[i] = off + s - v;
  if (tid == 255) bsum[blockIdx.x] = off + s;
}

__global__ __launch_bounds__(256) void k_scan2(
    int* __restrict__ bsum, int* __restrict__ rowptr, int M, int N)
{
  __shared__ int ws[4];
  __shared__ int carry_s;
  const int tid = threadIdx.x, lane = tid & 63, wv = tid >> 6;
  if (tid == 0) carry_s = 0;
  __syncthreads();
  for (int base = 0; base < M; base += 256) {
    int i = base + tid;
    int v = (i < M) ? bsum[i] : 0;
    int s = v;
    #pragma unroll
    for (int o = 1; o < 64; o <<= 1) { int t = __shfl_up(s, o); if (lane >= o) s += t; }
    if (lane == 63) ws[wv] = s;
    int c = carry_s;
    __syncthreads();
    int off = c;
    for (int k = 0; k < wv; ++k) off += ws[k];
    if (i < M) bsum[i] = off + s - v;
    __syncthreads();
    if (tid == 0) carry_s = c + ws[0] + ws[1] + ws[2] + ws[3];
    __syncthreads();
  }
  if (tid == 0) rowptr[N] = carry_s;
}

__global__ __launch_bounds__(256) void k_scan3(
    int* __restrict__ rowptr, const int* __restrict__ bsum, int N)
{
  int i = blockIdx.x * 256 + threadIdx.x;
  if (i < N) rowptr[i] += bsum[blockIdx.x];
}

__global__ __launch_bounds__(256) void k_scatter(
    const int* __restrict__ ei, const int* __restrict__ et,
    const int* __restrict__ rowptr, int* __restrict__ fill,
    unsigned* __restrict__ packed, int E)
{
  int e = blockIdx.x * 256 + threadIdx.x;
  if (e >= E) return;
  int d = ei[E + e];
  int pos = rowptr[d] + atomicAdd(&fill[d], 1);
  packed[pos] = (unsigned)ei[e] | ((unsigned)et[e] << 18);
}

// ---------- attention: wave-per-node, lane=(edge,head), in-lane 16-dim dot ----------
__global__ __launch_bounds__(256) void k_attn(
    const _Float16* __restrict__ qb, const _Float16* __restrict__ kvb,
    const unsigned* __restrict__ packed, const int* __restrict__ rowptr,
    const unsigned short* __restrict__ pc, unsigned short* __restrict__ msgb,
    int N, int th)
{
  __shared__ float ebs[64];
  const int tid = threadIdx.x, lane = tid & 63, wave = tid >> 6;
  if (tid < th) ebs[tid] = bf2f(pc[PC_EB + tid]);
  __syncthreads();
  const int n = blockIdx.x * 4 + wave;
  if (n >= N) return;
  const int h = lane & 7, el = lane >> 3;

  f16x8 qa, qc;
  {
    const _Float16* qp = qb + (size_t)n * 128 + h * 16;
    qa = *(const f16x8*)qp;
    qc = *(const f16x8*)(qp + 8);
  }
  const int beg = rowptr[n], end = rowptr[n + 1];
  float l = 0.f;
  f16x8 accA = {0, 0, 0, 0, 0, 0, 0, 0};
  f16x8 accB = {0, 0, 0, 0, 0, 0, 0, 0};

  if (beg < end) {
    int cur = min(beg + el, end - 1);
    unsigned pk = packed[cur];
    const _Float16* kp = kvb + (size_t)(pk & 0x3FFFF) * 256 + h * 32;
    f16x8 kA = *(const f16x8*)kp;
    f16x8 kB = *(const f16x8*)(kp + 8);
    f16x8 vA = *(const f16x8*)(kp + 16);
    f16x8 vB = *(const f16x8*)(kp + 24);
    for (int base = beg; base < end; base += 8) {
      int nxt = min(base + 8 + el, end - 1);
      unsigned pk2 = packed[nxt];
      const _Float16* kp2 = kvb + (size_t)(pk2 & 0x3FFFF) * 256 + h * 32;
      f16x8 kA2 = *(const f16x8*)kp2;
      f16x8 kB2 = *(const f16x8*)(kp2 + 8);
      f16x8 vA2 = *(const f16x8*)(kp2 + 16);
      f16x8 vB2 = *(const f16x8*)(kp2 + 24);

      float s = 0.f;
      #pragma unroll
      for (int j = 0; j < 4; ++j) {
        f16x2 a = {qa[2*j], qa[2*j+1]}, b = {kA[2*j], kA[2*j+1]};
        s = dot2(a, b, s);
      }
      #pragma unroll
      for (int j = 0; j < 4; ++j) {
        f16x2 a = {qc[2*j], qc[2*j+1]}, b = {kB[2*j], kB[2*j+1]};
        s = dot2(a, b, s);
      }
      float sc = fminf(s * 0.25f + ebs[(pk >> 18) * 8 + h], 80.f);
      float pe = (base + el < end) ? __expf(sc) : 0.f;
      l += pe;
      _Float16 pf = (_Float16)pe;
      f16x8 p8 = {pf, pf, pf, pf, pf, pf, pf, pf};
      accA += p8 * vA;
      accB += p8 * vB;

      pk = pk2; kA = kA2; kB = kB2; vA = vA2; vB = vB2;
    }
  }

  // reduce across the 8 edge-lanes sharing this head (xor 8,16,32)
  #pragma unroll
  for (int mask = 8; mask <= 32; mask <<= 1) {
    l += __shfl_xor(l, mask);
    int2 ai = bcast<int2>(accA), bi = bcast<int2>(accB);
    int2 as, bs;
    as.x = __shfl_xor(ai.x, mask); as.y = __shfl_xor(ai.y, mask);
    bs.x = __shfl_xor(bi.x, mask); bs.y = __shfl_xor(bi.y, mask);
    accA += bcast<f16x8>(as);
    accB += bcast<f16x8>(bs);
  }
  if (el == 0) {
    float inv = 1.f / (l + 1e-9f);
    unsigned o[8];
    #pragma unroll
    for (int j = 0; j < 4; ++j)
      o[j] = packbf((float)accA[2*j] * inv, (float)accA[2*j+1] * inv);
    #pragma unroll
    for (int j = 0; j < 4; ++j)
      o[4+j] = packbf((float)accB[2*j] * inv, (float)accB[2*j+1] * inv);
    uint4* dst = (uint4*)(msgb + (size_t)n * 128 + h * 16);
    uint4 d0 = {o[0], o[1], o[2], o[3]}, d1 = {o[4], o[5], o[6], o[7]};
    dst[0] = d0; dst[1] = d1;
  }
}

// ---------- fused tail: msg@wo+res -> LN2 -> FFN1(gelu) -> FFN2+res -> out ----------
__global__ __launch_bounds__(256) void k_tail(
    const void* __restrict__ xin, const int* __restrict__ flag,
    const unsigned short* __restrict__ msgb,
    const unsigned short* __restrict__ wop, const unsigned short* __restrict__ w1p,
    const unsigned short* __restrict__ w2p, const unsigned short* __restrict__ pc,
    void* __restrict__ out, int N)
{
  __shared__ unsigned short x1s[64 * 136];
  __shared__ unsigned short H[64 * 136];
  __shared__ unsigned short ts[64 * 264];
  const int tid = threadIdx.x;
  const int row0 = blockIdx.x * 64;
  const int isf = flag[0];
  const int wave = tid >> 6, lane = tid & 63;
  const int m = lane & 15, q = lane >> 4;
  const int rowb = wave * 16 + q * 4;

  {
    int rl = tid >> 2, c0 = (tid & 3) * 32;
    int r = row0 + rl;
    unsigned short hb[32];
    if (r < N) {
      if (isf) {
        const float4* xp = (const float4*)((const float*)xin + (size_t)r * 128 + c0);
        #pragma unroll
        for (int u = 0; u < 8; ++u) {
          float4 f = xp[u];
          hb[u*4] = f2bf(f.x); hb[u*4+1] = f2bf(f.y);
          hb[u*4+2] = f2bf(f.z); hb[u*4+3] = f2bf(f.w);
        }
      } else {
        const uint4* xp = (const uint4*)((const unsigned short*)xin + (size_t)r * 128 + c0);
        #pragma unroll
        for (int u = 0; u < 4; ++u) ((uint4*)hb)[u] = xp[u];
      }
    } else {
      #pragma unroll
      for (int u = 0; u < 32; ++u) hb[u] = 0;
    }
    #pragma unroll
    for (int u = 0; u < 4; ++u) ((uint4*)&x1s[rl * 136 + c0])[u] = ((const uint4*)hb)[u];
  }
  bf16x8 afr[4];
  {
    const unsigned short* ap = msgb + (size_t)min(row0 + wave * 16 + m, N - 1) * 128 + q * 8;
    #pragma unroll
    for (int ks = 0; ks < 4; ++ks) afr[ks] = *(const bf16x8*)&ap[ks * 32];
  }
  __syncthreads();

  for (int nt = 0; nt < 8; nt += 2) {
    const bf16x8* bp = (const bf16x8*)&wop[(size_t)(nt * 4 * 64 + lane) * 8];
    f32x4 acc0 = {0.f, 0.f, 0.f, 0.f}, acc1 = {0.f, 0.f, 0.f, 0.f};
    #pragma unroll
    for (int ks = 0; ks < 4; ++ks) {
      acc0 = __builtin_amdgcn_mfma_f32_16x16x32_bf16(afr[ks], bp[ks * 64],       acc0, 0, 0, 0);
      acc1 = __builtin_amdgcn_mfma_f32_16x16x32_bf16(afr[ks], bp[(4 + ks) * 64], acc1, 0, 0, 0);
    }
    #pragma unroll
    for (int tt = 0; tt < 2; ++tt) {
      f32x4 a = tt ? acc1 : acc0;
      int col = (nt + tt) * 16 + m;
      float bv = bf2f(pc[PC_BO + col]);
      #pragma unroll
      for (int rr = 0; rr < 4; ++rr) {
        int rl = rowb + rr;
        float o = a[rr] + bv + bf2f(x1s[rl * 136 + col]);
        x1s[rl * 136 + col] = f2bf(o);
      }
    }
  }
  __syncthreads();

  {
    int rl = tid >> 2, c0 = (tid & 3) * 32;
    unsigned short hb[32];
    #pragma unroll
    for (int u = 0; u < 4; ++u) ((uint4*)hb)[u] = *(const uint4*)&x1s[rl * 136 + c0 + u * 8];
    float xv[32];
    #pragma unroll
    for (int u = 0; u < 32; ++u) xv[u] = bf2f(hb[u]);
    float s = 0.f, s2 = 0.f;
    #pragma unroll
    for (int u = 0; u < 32; ++u) { s += xv[u]; s2 += xv[u] * xv[u]; }
    s += __shfl_xor(s, 1); s2 += __shfl_xor(s2, 1);
    s += __shfl_xor(s, 2); s2 += __shfl_xor(s2, 2);
    float mean = s * (1.f / 128.f);
    float var  = fmaxf(s2 * (1.f / 128.f) - mean * mean, 0.f);
    float inv  = rsqrtf(var + 1e-5f);
    #pragma unroll
    for (int u = 0; u < 32; ++u) {
      int c = c0 + u;
      hb[u] = f2bf((xv[u] - mean) * inv * bf2f(pc[PC_G2 + c]) + bf2f(pc[PC_B2 + c]));
    }
    #pragma unroll
    for (int u = 0; u < 4; ++u) ((uint4*)&H[rl * 136 + c0])[u] = ((const uint4*)hb)[u];
  }
  __syncthreads();

  bf16x8 hf[4];
  {
    const unsigned short* hp = &H[(wave * 16 + m) * 136 + q * 8];
    #pragma unroll
    for (int ks = 0; ks < 4; ++ks) hf[ks] = *(const bf16x8*)&hp[ks * 32];
  }
  for (int nt = 0; nt < 16; nt += 2) {
    const bf16x8* bp = (const bf16x8*)&w1p[(size_t)(nt * 4 * 64 + lane) * 8];
    f32x4 acc0 = {0.f, 0.f, 0.f, 0.f}, acc1 = {0.f, 0.f, 0.f, 0.f};
    #pragma unroll
    for (int ks = 0; ks < 4; ++ks) {
      acc0 = __builtin_amdgcn_mfma_f32_16x16x32_bf16(hf[ks], bp[ks * 64],       acc0, 0, 0, 0);
      acc1 = __builtin_amdgcn_mfma_f32_16x16x32_bf16(hf[ks], bp[(4 + ks) * 64], acc1, 0, 0, 0);
    }
    #pragma unroll
    for (int tt = 0; tt < 2; ++tt) {
      f32x4 a = tt ? acc1 : acc0;
      int col = (nt + tt) * 16 + m;
      float bv = bf2f(pc[PC_B1F + col]);
      #pragma unroll
      for (int rr = 0; rr < 4; ++rr)
        ts[(rowb + rr) * 264 + col] = f2bf(gelu_tanh(a[rr] + bv));
    }
  }
  __syncthreads();

  bf16x8 tf[8];
  {
    const unsigned short* tp = &ts[(wave * 16 + m) * 264 + q * 8];
    #pragma unroll
    for (int ks = 0; ks < 8; ++ks) tf[ks] = *(const bf16x8*)&tp[ks * 32];
  }
  for (int nt = 0; nt < 8; nt += 2) {
    const bf16x8* bp = (const bf16x8*)&w2p[(size_t)(nt * 8 * 64 + lane) * 8];
    f32x4 acc0 = {0.f, 0.f, 0.f, 0.f}, acc1 = {0.f, 0.f, 0.f, 0.f};
    #pragma unroll
    for (int ks = 0; ks < 8; ++ks) {
      acc0 = __builtin_amdgcn_mfma_f32_16x16x32_bf16(tf[ks], bp[ks * 64],       acc0, 0, 0, 0);
      acc1 = __builtin_amdgcn_mfma_f32_16x16x32_bf16(tf[ks], bp[(8 + ks) * 64], acc1, 0, 0, 0);
    }
    #pragma unroll
    for (int tt = 0; tt < 2; ++tt) {
      f32x4 a = tt ? acc1 : acc0;
      int col = (nt + tt) * 16 + m;
      float bv = bf2f(pc[PC_B2F + col]);
      #pragma unroll
      for (int rr = 0; rr < 4; ++rr) {
        int rl = rowb + rr;
        int row = row0 + rl;
        if (row < N) {
          float o = a[rr] + bv + bf2f(x1s[rl * 136 + col]);
          if (isf) ((float*)out)[(size_t)row * 128 + col] = o;
          else     ((unsigned short*)out)[(size_t)row * 128 + col] = f2bf(o);
        }
      }
    }
  }
}

// ---------- launch ----------
extern "C" void kernel_launch(void* const* d_in, const int* in_sizes, int n_in,
                              void* d_out, int out_size, void* d_ws, size_t ws_size,
                              hipStream_t stream)
{
  const void* x = d_in[0];
  const int* ei = (const int*)d_in[1];
  const int* et = (const int*)d_in[2];
  const int N = in_sizes[0] / 128;
  const int E = in_sizes[2];
  int th = in_sizes[13];
  if (th > 64) th = 64;

  char* ws = (char*)d_ws;
  size_t off = 0;
  auto alloc = [&](size_t bytes) -> void* {
    void* p = ws + off; off += (bytes + 255) & ~(size_t)255; return p;
  };
  int* flag = (int*)alloc(4);
  unsigned short* pc = (unsigned short*)alloc((size_t)PC_TOT * 2);
  _Float16* qb  = (_Float16*)alloc((size_t)N * 128 * 2);
  _Float16* kvb = (_Float16*)alloc((size_t)N * 256 * 2);
  unsigned* packed = (unsigned*)alloc((size_t)E * 4);
  int* rowptr = (int*)alloc((size_t)(N + 1) * 4);
  unsigned short* msgb = (unsigned short*)alloc((size_t)N * 128 * 2);
  unsigned short* wqkvp = (unsigned short*)alloc((size_t)128 * 384 * 2);
  unsigned short* wop   = (unsigned short*)alloc((size_t)128 * 128 * 2);
  unsigned short* w1p   = (unsigned short*)alloc((size_t)128 * 256 * 2);
  unsigned short* w2p   = (unsigned short*)alloc((size_t)256 * 128 * 2);
  unsigned short* bqkvb = (unsigned short*)alloc(384 * 2);
  const int SB = (N + 255) / 256;
  int* bsum = (int*)alloc((size_t)SB * 4);
  size_t zoff = off;
  int* deg  = (int*)alloc((size_t)N * 4);
  int* fill = (int*)alloc((size_t)N * 4);
  hipMemsetAsync(ws + zoff, 0, off - zoff, stream);

  k_detect<<<1, 256, 0, stream>>>((const unsigned*)x, flag);

  PP pp;
  for (int i = 0; i < 17; ++i) pp.p[i] = d_in[5 + i];
  k_prep<<<B_CONV + 66, 256, 0, stream>>>(pp, flag, pc, wqkvp, wop, w1p, w2p, bqkvb);

  const int NB = (N + 63) / 64;

  // LN1 + QKV (MFMA) -> qb(f16), kvb(f16 [h][k|v])
  k_lnqkv<<<NB, 256, 0, stream>>>(x, flag, pc, bqkvb, wqkvp, qb, kvb, N);

  // CSR build (multi-block scan)
  int eb = (E + 255) / 256;
  k_count<<<eb, 256, 0, stream>>>(ei, deg, E);
  k_scan1<<<SB, 256, 0, stream>>>(deg, rowptr, bsum, N);
  k_scan2<<<1, 256, 0, stream>>>(bsum, rowptr, SB, N);
  k_scan3<<<SB, 256, 0, stream>>>(rowptr, bsum, N);
  k_scatter<<<eb, 256, 0, stream>>>(ei, et, rowptr, fill, packed, E);

  // attention: wave-per-node, lane=(edge,head)
  k_attn<<<(N + 3) / 4, 256, 0, stream>>>(qb, kvb, packed, rowptr, pc, msgb, N, th);

  // fused tail
  k_tail<<<NB, 256, 0, stream>>>(x, flag, msgb, wop, w1p, w2p, pc, d_out, N);
}